// Round 6
// baseline (2014.220 us; speedup 1.0000x reference)
//
#include <hip/hip_runtime.h>
#include <hip/hip_bf16.h>
#include <string.h>

#define HID 128
#define NGRAPH 512
#define IN_DIM 384

typedef __attribute__((ext_vector_type(2))) float f32x2;

__device__ __forceinline__ float bf2f(unsigned short u) {
    unsigned int x = ((unsigned int)u) << 16;
    float f; __builtin_memcpy(&f, &x, 4); return f;
}
__device__ __forceinline__ unsigned short f2bf(float f) {
    unsigned int b; __builtin_memcpy(&b, &f, 4);
    unsigned int r = (b + 0x7FFFu + ((b >> 16) & 1u)) >> 16;   // RNE
    return (unsigned short)r;
}

// ---- GEMM body: hs8[v,:] = fp8_e4m3( (X[v,:] @ W) * dis[v] * 8 ) ----
template <int K, bool BF16IN>
__device__ __forceinline__ void gemm_body(float (*asT)[68], float* bs,
                                          const void* __restrict__ Xv,
                                          const float* __restrict__ W,
                                          const float* __restrict__ dis,
                                          unsigned int* __restrict__ out8,
                                          int n, int blk) {
    constexpr int KC = 32;
    const int t = threadIdx.x;
    const int tx = t & 31;   // col quad
    const int ty = t >> 5;   // row group
    const int row0 = blk * 64;

    float4 acc[8];
#pragma unroll
    for (int j = 0; j < 8; j++) acc[j] = make_float4(0.f, 0.f, 0.f, 0.f);

    const int ar = t >> 3;
    const int af = t & 7;

    for (int k0 = 0; k0 < K; k0 += KC) {
#pragma unroll
        for (int half = 0; half < 2; half++) {
            const int r = ar + half * 32;
            const int gr = row0 + r;
            float4 a = make_float4(0.f, 0.f, 0.f, 0.f);
            if (gr < n) {
                if constexpr (BF16IN) {
                    const ushort4 u = *(const ushort4*)((const unsigned short*)Xv + (long)gr * K + k0 + af * 4);
                    a.x = bf2f(u.x); a.y = bf2f(u.y); a.z = bf2f(u.z); a.w = bf2f(u.w);
                } else {
                    a = *(const float4*)((const float*)Xv + (long)gr * K + k0 + af * 4);
                }
            }
            asT[af * 4 + 0][r] = a.x;
            asT[af * 4 + 1][r] = a.y;
            asT[af * 4 + 2][r] = a.z;
            asT[af * 4 + 3][r] = a.w;
        }
        {
            const float4* wp = (const float4*)&W[(long)k0 * HID];
            float4* bp = (float4*)bs;
#pragma unroll
            for (int i = 0; i < 4; i++) bp[t + i * 256] = wp[t + i * 256];
        }
        __syncthreads();
#pragma unroll 8
        for (int kk = 0; kk < KC; kk++) {
            const float4 a0 = *(const float4*)&asT[kk][ty * 8];
            const float4 a1 = *(const float4*)&asT[kk][ty * 8 + 4];
            const float4 b  = *(const float4*)&bs[kk * HID + tx * 4];
            acc[0].x = fmaf(a0.x, b.x, acc[0].x); acc[0].y = fmaf(a0.x, b.y, acc[0].y);
            acc[0].z = fmaf(a0.x, b.z, acc[0].z); acc[0].w = fmaf(a0.x, b.w, acc[0].w);
            acc[1].x = fmaf(a0.y, b.x, acc[1].x); acc[1].y = fmaf(a0.y, b.y, acc[1].y);
            acc[1].z = fmaf(a0.y, b.z, acc[1].z); acc[1].w = fmaf(a0.y, b.w, acc[1].w);
            acc[2].x = fmaf(a0.z, b.x, acc[2].x); acc[2].y = fmaf(a0.z, b.y, acc[2].y);
            acc[2].z = fmaf(a0.z, b.z, acc[2].z); acc[2].w = fmaf(a0.z, b.w, acc[2].w);
            acc[3].x = fmaf(a0.w, b.x, acc[3].x); acc[3].y = fmaf(a0.w, b.y, acc[3].y);
            acc[3].z = fmaf(a0.w, b.z, acc[3].z); acc[3].w = fmaf(a0.w, b.w, acc[3].w);
            acc[4].x = fmaf(a1.x, b.x, acc[4].x); acc[4].y = fmaf(a1.x, b.y, acc[4].y);
            acc[4].z = fmaf(a1.x, b.z, acc[4].z); acc[4].w = fmaf(a1.x, b.w, acc[4].w);
            acc[5].x = fmaf(a1.y, b.x, acc[5].x); acc[5].y = fmaf(a1.y, b.y, acc[5].y);
            acc[5].z = fmaf(a1.y, b.z, acc[5].z); acc[5].w = fmaf(a1.y, b.w, acc[5].w);
            acc[6].x = fmaf(a1.z, b.x, acc[6].x); acc[6].y = fmaf(a1.z, b.y, acc[6].y);
            acc[6].z = fmaf(a1.z, b.z, acc[6].z); acc[6].w = fmaf(a1.z, b.w, acc[6].w);
            acc[7].x = fmaf(a1.w, b.x, acc[7].x); acc[7].y = fmaf(a1.w, b.y, acc[7].y);
            acc[7].z = fmaf(a1.w, b.z, acc[7].z); acc[7].w = fmaf(a1.w, b.w, acc[7].w);
        }
        __syncthreads();
    }

#pragma unroll
    for (int j = 0; j < 8; j++) {
        const int v = row0 + ty * 8 + j;
        if (v < n) {
            const float s = dis[v] * 8.0f;   // x8 keeps layer-2 messages out of e4m3 subnormals
            int w01 = __builtin_amdgcn_cvt_pk_fp8_f32(acc[j].x * s, acc[j].y * s, 0, false);
            int w   = __builtin_amdgcn_cvt_pk_fp8_f32(acc[j].z * s, acc[j].w * s, w01, true);
            out8[(long)v * (HID / 4) + tx] = (unsigned int)w;
        }
    }
}

// ---------------- degree ----------------
__global__ void deg_kernel(const int* __restrict__ dst, int* __restrict__ deg, int E) {
    int e = blockIdx.x * blockDim.x + threadIdx.x;
    if (e < E) atomicAdd(&deg[dst[e]], 1);
}

// ---------------- fused scan: deg -> row/cursor (exclusive), dis, row[n]=E ----------------
__global__ __launch_bounds__(1024) void scan_fused(const int* __restrict__ deg,
                                                   int* __restrict__ row,
                                                   int* __restrict__ cursor,
                                                   float* __restrict__ dis,
                                                   int n, int E) {
    __shared__ int ts[1024];
    const int t = threadIdx.x;
    const int CH = (n + 1023) >> 10;
    const int lo = t * CH;
    const int hi = min(lo + CH, n);
    int s = 0;
    for (int i = lo; i < hi; ++i) s += deg[i];
    ts[t] = s;
    __syncthreads();
    for (int off = 1; off < 1024; off <<= 1) {
        int x = (t >= off) ? ts[t - off] : 0;
        __syncthreads();
        ts[t] += x;
        __syncthreads();
    }
    int p = ts[t] - s;                          // exclusive prefix of this chunk
    for (int i = lo; i < hi; ++i) {
        const int d = deg[i];
        row[i] = p; cursor[i] = p;
        dis[i] = rsqrtf((float)(d + 1));        // +1 = self-loop
        p += d;
    }
    if (t == 0) row[n] = E;
}

// ---------------- fused gemm1 + CSR fill (CORRECT dependency order) ----------------
// Both consumers of scan_fused's outputs and mutually independent (gemm1: x,W1,dis->hs8;
// fill: src,dst,cursor->csr16). One grid: gemm blocks interleaved 1-per-'stride' among
// 4*edgeBlocks fill blocks (sweep k = dst range k). Block-dispatch order still runs
// sweep-0 blocks before sweep-3 blocks -> dst-range L2-residency trick approximately
// preserved; gemm1's VALU work hides the fill's atomic/scatter latency.
__global__ __launch_bounds__(256) void gemm1_fill(const float* __restrict__ X,
                                                  const float* __restrict__ W,
                                                  const float* __restrict__ dis,
                                                  unsigned int* __restrict__ out8, int n,
                                                  const int* __restrict__ src,
                                                  const int* __restrict__ dst,
                                                  int* __restrict__ cursor,
                                                  unsigned short* __restrict__ csr16,
                                                  int E, int gemmBlocks, int stride,
                                                  int edgeBlocks, int step) {
    __shared__ float asT[32][68];
    __shared__ float bs[32 * HID];
    const int bid = blockIdx.x;
    const bool isG = ((bid % stride) == 0) && ((bid / stride) < gemmBlocks);
    if (isG) {
        gemm_body<IN_DIM, false>(asT, bs, X, W, dis, out8, n, bid / stride);
    } else {
        const int gBefore = min((bid + stride - 1) / stride, gemmBlocks);
        const int fillIdx = bid - gBefore;                 // 0 .. 4*edgeBlocks-1
        const int sweep  = fillIdx / edgeBlocks;           // 0..3
        const int within = fillIdx - sweep * edgeBlocks;
        const int e = within * 256 + (int)threadIdx.x;
        if (e < E) {
            const int d = dst[e];
            const int lo = sweep * step;
            const int hi = (sweep == 3) ? n : (lo + step);
            if (d >= lo && d < hi) {
                int pos = atomicAdd(&cursor[d], 1);
                csr16[pos] = (unsigned short)src[e];
            }
        }
    }
}

// ---------------- gemm2 (bf16 input) ----------------
__global__ __launch_bounds__(256) void gemm_tile2(const unsigned short* __restrict__ X,
                                                  const float* __restrict__ W,
                                                  const float* __restrict__ dis,
                                                  unsigned int* __restrict__ out8, int n) {
    __shared__ float asT[32][68];
    __shared__ float bs[32 * HID];
    gemm_body<HID, true>(asT, bs, X, W, dis, out8, n, blockIdx.x);
}

// ---------------- gather aggregation + finalize (+ optional fused pool) ----------------
// Proven round-0 structure (locally converged: bytes at the 8xXCD*hs8 FETCH floor,
// 1 line/edge, ILP-insensitive). Inter-layer buffer stored as packed bf16.
template <bool POOL>
__global__ __launch_bounds__(256) void agg_kernel(const unsigned char* __restrict__ hs8,
                                                  const unsigned short* __restrict__ csr16,
                                                  const int* __restrict__ row,
                                                  const float* __restrict__ dis,
                                                  const float* __restrict__ bias,
                                                  const int* __restrict__ batch,
                                                  unsigned int* __restrict__ buf,   // bf16x2 packed
                                                  float* __restrict__ sums,
                                                  int* __restrict__ cnt, int n) {
    const int v = blockIdx.x * 4 + (threadIdx.x >> 6);
    if (v >= n) return;
    const int lane = threadIdx.x & 63;
    const int sub = lane >> 3;      // edge slot within pass (0..7)
    const int lc  = lane & 7;       // 16-byte chunk within row

    const int rs = row[v];
    const int re = row[v + 1];

    float acc[16];
#pragma unroll
    for (int i = 0; i < 16; i++) acc[i] = 0.f;

    for (int base = rs; base < re; base += 32) {
        uint4 w[4];
        int vld[4];
#pragma unroll
        for (int p = 0; p < 4; p++) {
            const int pe = base + p * 8;
            if (pe < re) {                       // wave-uniform guard
                const int ei = pe + sub;
                const int idx = __builtin_nontemporal_load(&csr16[(ei < re) ? ei : (re - 1)]);
                w[p] = *(const uint4*)&hs8[(long)idx * HID + (lc << 4)];
                vld[p] = (ei < re);
            } else {
                w[p] = make_uint4(0u, 0u, 0u, 0u);
                vld[p] = 0;
            }
        }
#pragma unroll
        for (int p = 0; p < 4; p++) {
            if (vld[p]) {
                const uint4 ww = w[p];
                f32x2 u;
                u = __builtin_amdgcn_cvt_pk_f32_fp8(ww.x, false); acc[0]  += u.x; acc[1]  += u.y;
                u = __builtin_amdgcn_cvt_pk_f32_fp8(ww.x, true);  acc[2]  += u.x; acc[3]  += u.y;
                u = __builtin_amdgcn_cvt_pk_f32_fp8(ww.y, false); acc[4]  += u.x; acc[5]  += u.y;
                u = __builtin_amdgcn_cvt_pk_f32_fp8(ww.y, true);  acc[6]  += u.x; acc[7]  += u.y;
                u = __builtin_amdgcn_cvt_pk_f32_fp8(ww.z, false); acc[8]  += u.x; acc[9]  += u.y;
                u = __builtin_amdgcn_cvt_pk_f32_fp8(ww.z, true);  acc[10] += u.x; acc[11] += u.y;
                u = __builtin_amdgcn_cvt_pk_f32_fp8(ww.w, false); acc[12] += u.x; acc[13] += u.y;
                u = __builtin_amdgcn_cvt_pk_f32_fp8(ww.w, true);  acc[14] += u.x; acc[15] += u.y;
            }
        }
    }

    // fold the 8 sub-groups (lanes differing in bits 3..5, same lc)
#pragma unroll
    for (int i = 0; i < 16; i++) {
        acc[i] += __shfl_xor(acc[i], 8, 64);
        acc[i] += __shfl_xor(acc[i], 16, 64);
        acc[i] += __shfl_xor(acc[i], 32, 64);
    }

    // each lane owns cols col, col+1 where col = 16*lc + 2*sub
    const int col = (lc << 4) + (sub << 1);
    const unsigned short selfw = *(const unsigned short*)&hs8[(long)v * HID + col];
    f32x2 sf = __builtin_amdgcn_cvt_pk_f32_fp8((unsigned int)selfw, false);
    const float sx = acc[(sub << 1) + 0] + sf.x;
    const float sy = acc[(sub << 1) + 1] + sf.y;
    const float dv = dis[v] * 0.125f;   // undo the x8 message scale
    const float rx = fmaxf(fmaf(dv, sx, bias[col]), 0.f);
    const float ry = fmaxf(fmaf(dv, sy, bias[col + 1]), 0.f);
    if (POOL) {
        const int g = batch[v];
        unsafeAtomicAdd(&sums[g * HID + col], rx);
        unsafeAtomicAdd(&sums[g * HID + col + 1], ry);
        if (lane == 0) atomicAdd(&cnt[g], 1);
    } else {
        const unsigned int pk = (unsigned int)f2bf(rx) | ((unsigned int)f2bf(ry) << 16);
        buf[(long)v * (HID / 2) + (col >> 1)] = pk;      // col is even
    }
}

// ---------------- mean + MLP head ----------------
__global__ __launch_bounds__(64) void mlp_kernel(const float* __restrict__ sums,
                                                 const int* __restrict__ cnt,
                                                 const float* __restrict__ Wl1,
                                                 const float* __restrict__ bl1,
                                                 const float* __restrict__ Wl2,
                                                 const float* __restrict__ bl2,
                                                 float* __restrict__ out) {
    const int g = blockIdx.x, t = threadIdx.x;
    __shared__ float mean[HID];
    __shared__ float hid[64];
    const float c = fmaxf((float)cnt[g], 1.0f);
    mean[t] = sums[g * HID + t] / c;
    mean[t + 64] = sums[g * HID + 64 + t] / c;
    __syncthreads();
    float acc = bl1[t];
#pragma unroll 4
    for (int k = 0; k < HID; k++) acc = fmaf(mean[k], Wl1[k * 64 + t], acc);
    hid[t] = fmaxf(acc, 0.f);
    __syncthreads();
    if (t < 5) {
        float a = bl2[t];
#pragma unroll 4
        for (int k = 0; k < 64; k++) a = fmaf(hid[k], Wl2[k * 5 + t], a);
        out[g * 5 + t] = 1.f / (1.f + expf(-a));
    }
}

extern "C" void kernel_launch(void* const* d_in, const int* in_sizes, int n_in,
                              void* d_out, int out_size, void* d_ws, size_t ws_size,
                              hipStream_t stream) {
    const float* x   = (const float*)d_in[0];
    const int* ei    = (const int*)d_in[1];
    const int* batch = (const int*)d_in[2];
    const float* W1  = (const float*)d_in[3];
    const float* b1  = (const float*)d_in[4];
    const float* W2  = (const float*)d_in[5];
    const float* b2  = (const float*)d_in[6];
    const float* Wl1 = (const float*)d_in[7];
    const float* bl1 = (const float*)d_in[8];
    const float* Wl2 = (const float*)d_in[9];
    const float* bl2 = (const float*)d_in[10];
    float* out = (float*)d_out;

    const int n = in_sizes[0] / IN_DIM;       // 50000
    const int E = in_sizes[1] / 2;            // 1600000
    const int* src = ei;
    const int* dst = ei + E;

    char* ws = (char*)d_ws;
    size_t off = 0;
    auto alloc = [&](size_t bytes) {
        void* p = ws + off;
        off = (off + bytes + 255) & ~(size_t)255;
        return p;
    };
    int*   deg       = (int*)alloc((size_t)n * 4);
    float* dis       = (float*)alloc((size_t)n * 4);
    int*   row       = (int*)alloc((size_t)(n + 1) * 4);
    int*   cursor    = (int*)alloc((size_t)n * 4);
    unsigned short* csr16 = (unsigned short*)alloc((size_t)E * 2);
    unsigned char* hs8 = (unsigned char*)alloc((size_t)n * HID);       // fp8 messages
    unsigned int* buf1 = (unsigned int*)alloc((size_t)n * HID * 2);    // bf16 inter-layer h
    float* sums = (float*)alloc((size_t)NGRAPH * HID * 4);             // 256-mult ->
    int*   cnt  = (int*)alloc((size_t)NGRAPH * 4);                     // contiguous with sums
    (void)ws_size;

    const int gemmBlocks = (n + 63) / 64;                  // 782
    const int aggBlocks  = (n + 3) / 4;
    const int edgeBlocks = (E + 255) / 256;                // 6250
    const int step       = (n + 3) / 4;                    // dst-range per sweep
    const int fusedTot   = gemmBlocks + 4 * edgeBlocks;    // 25782
    const int stride     = max(1, fusedTot / gemmBlocks);  // ~32

    // --- zero deg + (sums,cnt contiguous: one memset) ---
    hipMemsetAsync(deg, 0, (size_t)n * 4, stream);
    hipMemsetAsync(sums, 0, (size_t)NGRAPH * HID * 4 + (size_t)NGRAPH * 4, stream);

    // --- degree (needs only dst) ---
    deg_kernel<<<edgeBlocks, 256, 0, stream>>>(dst, deg, E);

    // --- scan (+dis, +cursor init): 1 launch ---
    scan_fused<<<1, 1024, 0, stream>>>(deg, row, cursor, dis, n, E);

    // --- conv1 transform || CSR fill (both depend only on scan outputs; one grid) ---
    gemm1_fill<<<fusedTot, 256, 0, stream>>>(x, W1, dis, (unsigned int*)hs8, n,
                                             src, dst, cursor, csr16, E,
                                             gemmBlocks, stride, edgeBlocks, step);

    // --- conv1 aggregate ---
    agg_kernel<false><<<aggBlocks, 256, 0, stream>>>(hs8, csr16, row, dis, b1, batch,
                                                     buf1, nullptr, nullptr, n);

    // --- conv2 (pool fused) ---
    gemm_tile2<<<gemmBlocks, 256, 0, stream>>>((const unsigned short*)buf1, W2, dis,
                                               (unsigned int*)hs8, n);
    agg_kernel<true><<<aggBlocks, 256, 0, stream>>>(hs8, csr16, row, dis, b2, batch,
                                                    nullptr, sums, cnt, n);

    // --- head ---
    mlp_kernel<<<NGRAPH, 64, 0, stream>>>(sums, cnt, Wl1, bl1, Wl2, bl2, out);
}

// Round 7
// 706.430 us; speedup vs baseline: 2.8513x; 2.8513x over previous
//
#include <hip/hip_runtime.h>
#include <hip/hip_bf16.h>
#include <string.h>

#define HID 128
#define NGRAPH 512
#define IN_DIM 384

typedef __attribute__((ext_vector_type(2))) float f32x2;

__device__ __forceinline__ float bf2f(unsigned short u) {
    unsigned int x = ((unsigned int)u) << 16;
    float f; __builtin_memcpy(&f, &x, 4); return f;
}
__device__ __forceinline__ unsigned short f2bf(float f) {
    unsigned int b; __builtin_memcpy(&b, &f, 4);
    unsigned int r = (b + 0x7FFFu + ((b >> 16) & 1u)) >> 16;   // RNE
    return (unsigned short)r;
}

// ---------------- degree ----------------
__global__ void deg_kernel(const int* __restrict__ dst, int* __restrict__ deg, int E) {
    int e = blockIdx.x * blockDim.x + threadIdx.x;
    if (e < E) atomicAdd(&deg[dst[e]], 1);
}

// ---------------- fused scan: deg -> row/cursor (exclusive), dis, row[n]=E ----------------
// Replaces dis + scan_part + scan_tops + scan_add (4 launches -> 1). Correctness
// verified in R6 (passed absmax with this kernel in the chain).
__global__ __launch_bounds__(1024) void scan_fused(const int* __restrict__ deg,
                                                   int* __restrict__ row,
                                                   int* __restrict__ cursor,
                                                   float* __restrict__ dis,
                                                   int n, int E) {
    __shared__ int ts[1024];
    const int t = threadIdx.x;
    const int CH = (n + 1023) >> 10;
    const int lo = t * CH;
    const int hi = min(lo + CH, n);
    int s = 0;
    for (int i = lo; i < hi; ++i) s += deg[i];
    ts[t] = s;
    __syncthreads();
    for (int off = 1; off < 1024; off <<= 1) {
        int x = (t >= off) ? ts[t - off] : 0;
        __syncthreads();
        ts[t] += x;
        __syncthreads();
    }
    int p = ts[t] - s;                          // exclusive prefix of this chunk
    for (int i = lo; i < hi; ++i) {
        const int d = deg[i];
        row[i] = p; cursor[i] = p;
        dis[i] = rsqrtf((float)(d + 1));        // +1 = self-loop
        p += d;
    }
    if (t == 0) row[n] = E;
}

// ---------------- CSR fill (ushort src ids, dst-range sweep; NO LDS -> full occupancy) ----------------
// R6 lesson: keep fill as its own lean kernel. 4 serialized dst-range sweeps keep
// csr16 writes confined to a dense ~800 KB region (low writeback amplification).
__global__ void fill_kernel(const int* __restrict__ src, const int* __restrict__ dst,
                            int* __restrict__ cursor, unsigned short* __restrict__ csr16,
                            int E, int lo, int hi) {
    int e = blockIdx.x * blockDim.x + threadIdx.x;
    if (e < E) {
        const int d = dst[e];
        if (d >= lo && d < hi) {
            int pos = atomicAdd(&cursor[d], 1);
            csr16[pos] = (unsigned short)src[e];
        }
    }
}

// ---- tiled register-blocked GEMM: hs8[v,:] = fp8_e4m3( (X[v,:] @ W) * dis[v] * 8 ) ----
// BF16IN: X is bf16 [n][K] (the inter-layer buffer); converted to f32 during LDS staging.
template <int K, bool BF16IN>
__global__ __launch_bounds__(256) void gemm_tile(const void* __restrict__ Xv,
                                                 const float* __restrict__ W,
                                                 const float* __restrict__ dis,
                                                 unsigned int* __restrict__ out8, int n) {
    constexpr int KC = 32;
    __shared__ float asT[KC][68];
    __shared__ float bs[KC * HID];
    const int t = threadIdx.x;
    const int tx = t & 31;   // col quad
    const int ty = t >> 5;   // row group
    const int row0 = blockIdx.x * 64;

    float4 acc[8];
#pragma unroll
    for (int j = 0; j < 8; j++) acc[j] = make_float4(0.f, 0.f, 0.f, 0.f);

    const int ar = t >> 3;
    const int af = t & 7;

    for (int k0 = 0; k0 < K; k0 += KC) {
#pragma unroll
        for (int half = 0; half < 2; half++) {
            const int r = ar + half * 32;
            const int gr = row0 + r;
            float4 a = make_float4(0.f, 0.f, 0.f, 0.f);
            if (gr < n) {
                if constexpr (BF16IN) {
                    const ushort4 u = *(const ushort4*)((const unsigned short*)Xv + (long)gr * K + k0 + af * 4);
                    a.x = bf2f(u.x); a.y = bf2f(u.y); a.z = bf2f(u.z); a.w = bf2f(u.w);
                } else {
                    a = *(const float4*)((const float*)Xv + (long)gr * K + k0 + af * 4);
                }
            }
            asT[af * 4 + 0][r] = a.x;
            asT[af * 4 + 1][r] = a.y;
            asT[af * 4 + 2][r] = a.z;
            asT[af * 4 + 3][r] = a.w;
        }
        {
            const float4* wp = (const float4*)&W[(long)k0 * HID];
            float4* bp = (float4*)bs;
#pragma unroll
            for (int i = 0; i < 4; i++) bp[t + i * 256] = wp[t + i * 256];
        }
        __syncthreads();
#pragma unroll 8
        for (int kk = 0; kk < KC; kk++) {
            const float4 a0 = *(const float4*)&asT[kk][ty * 8];
            const float4 a1 = *(const float4*)&asT[kk][ty * 8 + 4];
            const float4 b  = *(const float4*)&bs[kk * HID + tx * 4];
            acc[0].x = fmaf(a0.x, b.x, acc[0].x); acc[0].y = fmaf(a0.x, b.y, acc[0].y);
            acc[0].z = fmaf(a0.x, b.z, acc[0].z); acc[0].w = fmaf(a0.x, b.w, acc[0].w);
            acc[1].x = fmaf(a0.y, b.x, acc[1].x); acc[1].y = fmaf(a0.y, b.y, acc[1].y);
            acc[1].z = fmaf(a0.y, b.z, acc[1].z); acc[1].w = fmaf(a0.y, b.w, acc[1].w);
            acc[2].x = fmaf(a0.z, b.x, acc[2].x); acc[2].y = fmaf(a0.z, b.y, acc[2].y);
            acc[2].z = fmaf(a0.z, b.z, acc[2].z); acc[2].w = fmaf(a0.z, b.w, acc[2].w);
            acc[3].x = fmaf(a0.w, b.x, acc[3].x); acc[3].y = fmaf(a0.w, b.y, acc[3].y);
            acc[3].z = fmaf(a0.w, b.z, acc[3].z); acc[3].w = fmaf(a0.w, b.w, acc[3].w);
            acc[4].x = fmaf(a1.x, b.x, acc[4].x); acc[4].y = fmaf(a1.x, b.y, acc[4].y);
            acc[4].z = fmaf(a1.x, b.z, acc[4].z); acc[4].w = fmaf(a1.x, b.w, acc[4].w);
            acc[5].x = fmaf(a1.y, b.x, acc[5].x); acc[5].y = fmaf(a1.y, b.y, acc[5].y);
            acc[5].z = fmaf(a1.y, b.z, acc[5].z); acc[5].w = fmaf(a1.y, b.w, acc[5].w);
            acc[6].x = fmaf(a1.z, b.x, acc[6].x); acc[6].y = fmaf(a1.z, b.y, acc[6].y);
            acc[6].z = fmaf(a1.z, b.z, acc[6].z); acc[6].w = fmaf(a1.z, b.w, acc[6].w);
            acc[7].x = fmaf(a1.w, b.x, acc[7].x); acc[7].y = fmaf(a1.w, b.y, acc[7].y);
            acc[7].z = fmaf(a1.w, b.z, acc[7].z); acc[7].w = fmaf(a1.w, b.w, acc[7].w);
        }
        __syncthreads();
    }

#pragma unroll
    for (int j = 0; j < 8; j++) {
        const int v = row0 + ty * 8 + j;
        if (v < n) {
            const float s = dis[v] * 8.0f;   // x8 keeps layer-2 messages out of e4m3 subnormals
            int w01 = __builtin_amdgcn_cvt_pk_fp8_f32(acc[j].x * s, acc[j].y * s, 0, false);
            int w   = __builtin_amdgcn_cvt_pk_fp8_f32(acc[j].z * s, acc[j].w * s, w01, true);
            out8[(long)v * (HID / 4) + tx] = (unsigned int)w;
        }
    }
}

// ---------------- gather aggregation + finalize (+ optional fused pool) ----------------
// Proven round-0 structure (locally converged: FETCH at the 8xXCD*hs8 floor,
// 1 line/edge, ILP-insensitive). Inter-layer buffer stored as packed bf16.
template <bool POOL>
__global__ __launch_bounds__(256) void agg_kernel(const unsigned char* __restrict__ hs8,
                                                  const unsigned short* __restrict__ csr16,
                                                  const int* __restrict__ row,
                                                  const float* __restrict__ dis,
                                                  const float* __restrict__ bias,
                                                  const int* __restrict__ batch,
                                                  unsigned int* __restrict__ buf,   // bf16x2 packed
                                                  float* __restrict__ sums,
                                                  int* __restrict__ cnt, int n) {
    const int v = blockIdx.x * 4 + (threadIdx.x >> 6);
    if (v >= n) return;
    const int lane = threadIdx.x & 63;
    const int sub = lane >> 3;      // edge slot within pass (0..7)
    const int lc  = lane & 7;       // 16-byte chunk within row

    const int rs = row[v];
    const int re = row[v + 1];

    float acc[16];
#pragma unroll
    for (int i = 0; i < 16; i++) acc[i] = 0.f;

    for (int base = rs; base < re; base += 32) {
        uint4 w[4];
        int vld[4];
#pragma unroll
        for (int p = 0; p < 4; p++) {
            const int pe = base + p * 8;
            if (pe < re) {                       // wave-uniform guard
                const int ei = pe + sub;
                const int idx = __builtin_nontemporal_load(&csr16[(ei < re) ? ei : (re - 1)]);
                w[p] = *(const uint4*)&hs8[(long)idx * HID + (lc << 4)];
                vld[p] = (ei < re);
            } else {
                w[p] = make_uint4(0u, 0u, 0u, 0u);
                vld[p] = 0;
            }
        }
#pragma unroll
        for (int p = 0; p < 4; p++) {
            if (vld[p]) {
                const uint4 ww = w[p];
                f32x2 u;
                u = __builtin_amdgcn_cvt_pk_f32_fp8(ww.x, false); acc[0]  += u.x; acc[1]  += u.y;
                u = __builtin_amdgcn_cvt_pk_f32_fp8(ww.x, true);  acc[2]  += u.x; acc[3]  += u.y;
                u = __builtin_amdgcn_cvt_pk_f32_fp8(ww.y, false); acc[4]  += u.x; acc[5]  += u.y;
                u = __builtin_amdgcn_cvt_pk_f32_fp8(ww.y, true);  acc[6]  += u.x; acc[7]  += u.y;
                u = __builtin_amdgcn_cvt_pk_f32_fp8(ww.z, false); acc[8]  += u.x; acc[9]  += u.y;
                u = __builtin_amdgcn_cvt_pk_f32_fp8(ww.z, true);  acc[10] += u.x; acc[11] += u.y;
                u = __builtin_amdgcn_cvt_pk_f32_fp8(ww.w, false); acc[12] += u.x; acc[13] += u.y;
                u = __builtin_amdgcn_cvt_pk_f32_fp8(ww.w, true);  acc[14] += u.x; acc[15] += u.y;
            }
        }
    }

    // fold the 8 sub-groups (lanes differing in bits 3..5, same lc)
#pragma unroll
    for (int i = 0; i < 16; i++) {
        acc[i] += __shfl_xor(acc[i], 8, 64);
        acc[i] += __shfl_xor(acc[i], 16, 64);
        acc[i] += __shfl_xor(acc[i], 32, 64);
    }

    // each lane owns cols col, col+1 where col = 16*lc + 2*sub
    const int col = (lc << 4) + (sub << 1);
    const unsigned short selfw = *(const unsigned short*)&hs8[(long)v * HID + col];
    f32x2 sf = __builtin_amdgcn_cvt_pk_f32_fp8((unsigned int)selfw, false);
    const float sx = acc[(sub << 1) + 0] + sf.x;
    const float sy = acc[(sub << 1) + 1] + sf.y;
    const float dv = dis[v] * 0.125f;   // undo the x8 message scale
    const float rx = fmaxf(fmaf(dv, sx, bias[col]), 0.f);
    const float ry = fmaxf(fmaf(dv, sy, bias[col + 1]), 0.f);
    if (POOL) {
        const int g = batch[v];
        unsafeAtomicAdd(&sums[g * HID + col], rx);
        unsafeAtomicAdd(&sums[g * HID + col + 1], ry);
        if (lane == 0) atomicAdd(&cnt[g], 1);
    } else {
        const unsigned int pk = (unsigned int)f2bf(rx) | ((unsigned int)f2bf(ry) << 16);
        buf[(long)v * (HID / 2) + (col >> 1)] = pk;      // col is even
    }
}

// ---------------- mean + MLP head ----------------
__global__ __launch_bounds__(64) void mlp_kernel(const float* __restrict__ sums,
                                                 const int* __restrict__ cnt,
                                                 const float* __restrict__ Wl1,
                                                 const float* __restrict__ bl1,
                                                 const float* __restrict__ Wl2,
                                                 const float* __restrict__ bl2,
                                                 float* __restrict__ out) {
    const int g = blockIdx.x, t = threadIdx.x;
    __shared__ float mean[HID];
    __shared__ float hid[64];
    const float c = fmaxf((float)cnt[g], 1.0f);
    mean[t] = sums[g * HID + t] / c;
    mean[t + 64] = sums[g * HID + 64 + t] / c;
    __syncthreads();
    float acc = bl1[t];
#pragma unroll 4
    for (int k = 0; k < HID; k++) acc = fmaf(mean[k], Wl1[k * 64 + t], acc);
    hid[t] = fmaxf(acc, 0.f);
    __syncthreads();
    if (t < 5) {
        float a = bl2[t];
#pragma unroll 4
        for (int k = 0; k < 64; k++) a = fmaf(hid[k], Wl2[k * 5 + t], a);
        out[g * 5 + t] = 1.f / (1.f + expf(-a));
    }
}

extern "C" void kernel_launch(void* const* d_in, const int* in_sizes, int n_in,
                              void* d_out, int out_size, void* d_ws, size_t ws_size,
                              hipStream_t stream) {
    const float* x   = (const float*)d_in[0];
    const int* ei    = (const int*)d_in[1];
    const int* batch = (const int*)d_in[2];
    const float* W1  = (const float*)d_in[3];
    const float* b1  = (const float*)d_in[4];
    const float* W2  = (const float*)d_in[5];
    const float* b2  = (const float*)d_in[6];
    const float* Wl1 = (const float*)d_in[7];
    const float* bl1 = (const float*)d_in[8];
    const float* Wl2 = (const float*)d_in[9];
    const float* bl2 = (const float*)d_in[10];
    float* out = (float*)d_out;

    const int n = in_sizes[0] / IN_DIM;       // 50000
    const int E = in_sizes[1] / 2;            // 1600000
    const int* src = ei;
    const int* dst = ei + E;

    char* ws = (char*)d_ws;
    size_t off = 0;
    auto alloc = [&](size_t bytes) {
        void* p = ws + off;
        off = (off + bytes + 255) & ~(size_t)255;
        return p;
    };
    int*   deg       = (int*)alloc((size_t)n * 4);
    float* dis       = (float*)alloc((size_t)n * 4);
    int*   row       = (int*)alloc((size_t)(n + 1) * 4);
    int*   cursor    = (int*)alloc((size_t)n * 4);
    unsigned short* csr16 = (unsigned short*)alloc((size_t)E * 2);
    unsigned char* hs8 = (unsigned char*)alloc((size_t)n * HID);       // fp8 messages
    unsigned int* buf1 = (unsigned int*)alloc((size_t)n * HID * 2);    // bf16 inter-layer h
    float* sums = (float*)alloc((size_t)NGRAPH * HID * 4);             // 256-mult ->
    int*   cnt  = (int*)alloc((size_t)NGRAPH * 4);                     // contiguous with sums
    (void)ws_size;

    const int gemmBlocks = (n + 63) / 64;
    const int aggBlocks  = (n + 3) / 4;
    const int edgeBlocks = (E + 255) / 256;

    // --- zero deg + (sums,cnt contiguous: one memset) ---
    hipMemsetAsync(deg, 0, (size_t)n * 4, stream);
    hipMemsetAsync(sums, 0, (size_t)NGRAPH * HID * 4 + (size_t)NGRAPH * 4, stream);

    // --- degree ---
    deg_kernel<<<edgeBlocks, 256, 0, stream>>>(dst, deg, E);

    // --- scan (+dis, +cursor init): 1 launch ---
    scan_fused<<<1, 1024, 0, stream>>>(deg, row, cursor, dis, n, E);

    // --- CSR fill: 4 dst-range sweeps (separate lean kernel; R6 lesson) ---
    {
        const int step = (n + 3) / 4;
        for (int k = 0; k < 4; k++) {
            const int lo = k * step;
            const int hi = (k == 3) ? n : (lo + step);
            fill_kernel<<<edgeBlocks, 256, 0, stream>>>(src, dst, cursor, csr16, E, lo, hi);
        }
    }

    // --- conv1 ---
    gemm_tile<IN_DIM, false><<<gemmBlocks, 256, 0, stream>>>(x, W1, dis, (unsigned int*)hs8, n);
    agg_kernel<false><<<aggBlocks, 256, 0, stream>>>(hs8, csr16, row, dis, b1, batch,
                                                     buf1, nullptr, nullptr, n);

    // --- conv2 (pool fused) ---
    gemm_tile<HID, true><<<gemmBlocks, 256, 0, stream>>>(buf1, W2, dis, (unsigned int*)hs8, n);
    agg_kernel<true><<<aggBlocks, 256, 0, stream>>>(hs8, csr16, row, dis, b2, batch,
                                                    nullptr, sums, cnt, n);

    // --- head ---
    mlp_kernel<<<NGRAPH, 64, 0, stream>>>(sums, cnt, Wl1, bl1, Wl2, bl2, out);
}

// Round 8
// 584.735 us; speedup vs baseline: 3.4447x; 1.2081x over previous
//
#include <hip/hip_runtime.h>
#include <hip/hip_bf16.h>
#include <string.h>

#define HID 128
#define NGRAPH 512
#define IN_DIM 384

typedef __attribute__((ext_vector_type(2))) float f32x2;

__device__ __forceinline__ float bf2f(unsigned short u) {
    unsigned int x = ((unsigned int)u) << 16;
    float f; __builtin_memcpy(&f, &x, 4); return f;
}
__device__ __forceinline__ unsigned short f2bf(float f) {
    unsigned int b; __builtin_memcpy(&b, &f, 4);
    unsigned int r = (b + 0x7FFFu + ((b >> 16) & 1u)) >> 16;   // RNE
    return (unsigned short)r;
}

// ---------------- degree ----------------
__global__ void deg_kernel(const int* __restrict__ dst, int* __restrict__ deg, int E) {
    int e = blockIdx.x * blockDim.x + threadIdx.x;
    if (e < E) atomicAdd(&deg[dst[e]], 1);
}

__global__ void dis_kernel(const int* __restrict__ deg, float* __restrict__ dis, int n) {
    int v = blockIdx.x * blockDim.x + threadIdx.x;
    if (v < n) dis[v] = rsqrtf((float)(deg[v] + 1));  // +1 = self-loop
}

// ---------------- exclusive scan of deg -> row_start (multi-block; R7 lesson:
// a single-workgroup scan is 137us of serial latency — keep 49 blocks busy) ----
__global__ __launch_bounds__(256) void scan_part(const int* __restrict__ deg, int* __restrict__ row,
                                                 int* __restrict__ blockSums, int n) {
    __shared__ int ts[256];
    const int b = blockIdx.x, t = threadIdx.x;
    const int base = b * 1024 + t * 4;
    int v0 = (base + 0 < n) ? deg[base + 0] : 0;
    int v1 = (base + 1 < n) ? deg[base + 1] : 0;
    int v2 = (base + 2 < n) ? deg[base + 2] : 0;
    int v3 = (base + 3 < n) ? deg[base + 3] : 0;
    const int s = v0 + v1 + v2 + v3;
    ts[t] = s;
    __syncthreads();
    for (int off = 1; off < 256; off <<= 1) {
        int x = (t >= off) ? ts[t - off] : 0;
        __syncthreads();
        ts[t] += x;
        __syncthreads();
    }
    int p = ts[t] - s;
    if (base + 0 < n) { row[base + 0] = p; p += v0; }
    if (base + 1 < n) { row[base + 1] = p; p += v1; }
    if (base + 2 < n) { row[base + 2] = p; p += v2; }
    if (base + 3 < n) { row[base + 3] = p; }
    if (t == 255) blockSums[b] = ts[255];
}

__global__ void scan_tops(int* __restrict__ blockSums, int nb) {
    if (threadIdx.x == 0 && blockIdx.x == 0) {
        int acc = 0;
        for (int i = 0; i < nb; i++) { int v = blockSums[i]; blockSums[i] = acc; acc += v; }
    }
}

__global__ __launch_bounds__(256) void scan_add(int* __restrict__ row, int* __restrict__ cursor,
                                                const int* __restrict__ blockSums, int n, int E) {
    const int b = blockIdx.x, t = threadIdx.x;
    const int off = blockSums[b];
    const int base = b * 1024 + t * 4;
#pragma unroll
    for (int j = 0; j < 4; j++) {
        int i = base + j;
        if (i < n) { int v = row[i] + off; row[i] = v; cursor[i] = v; }
    }
    if (b == 0 && t == 0) row[n] = E;
}

// ---------------- CSR fill (ushort src ids, dst-range sweep; lean, no LDS) ----------------
__global__ void fill_kernel(const int* __restrict__ src, const int* __restrict__ dst,
                            int* __restrict__ cursor, unsigned short* __restrict__ csr16,
                            int E, int lo, int hi) {
    int e = blockIdx.x * blockDim.x + threadIdx.x;
    if (e < E) {
        const int d = dst[e];
        if (d >= lo && d < hi) {
            int pos = atomicAdd(&cursor[d], 1);
            csr16[pos] = (unsigned short)src[e];
        }
    }
}

// ---- tiled register-blocked GEMM: hs8[v,:] = fp8_e4m3( (X[v,:] @ W) * dis[v] * 8 ) ----
// BF16IN: X is bf16 [n][K] (the inter-layer buffer); converted to f32 during LDS staging.
template <int K, bool BF16IN>
__global__ __launch_bounds__(256) void gemm_tile(const void* __restrict__ Xv,
                                                 const float* __restrict__ W,
                                                 const float* __restrict__ dis,
                                                 unsigned int* __restrict__ out8, int n) {
    constexpr int KC = 32;
    __shared__ float asT[KC][68];
    __shared__ float bs[KC * HID];
    const int t = threadIdx.x;
    const int tx = t & 31;   // col quad
    const int ty = t >> 5;   // row group
    const int row0 = blockIdx.x * 64;

    float4 acc[8];
#pragma unroll
    for (int j = 0; j < 8; j++) acc[j] = make_float4(0.f, 0.f, 0.f, 0.f);

    const int ar = t >> 3;
    const int af = t & 7;

    for (int k0 = 0; k0 < K; k0 += KC) {
#pragma unroll
        for (int half = 0; half < 2; half++) {
            const int r = ar + half * 32;
            const int gr = row0 + r;
            float4 a = make_float4(0.f, 0.f, 0.f, 0.f);
            if (gr < n) {
                if constexpr (BF16IN) {
                    const ushort4 u = *(const ushort4*)((const unsigned short*)Xv + (long)gr * K + k0 + af * 4);
                    a.x = bf2f(u.x); a.y = bf2f(u.y); a.z = bf2f(u.z); a.w = bf2f(u.w);
                } else {
                    a = *(const float4*)((const float*)Xv + (long)gr * K + k0 + af * 4);
                }
            }
            asT[af * 4 + 0][r] = a.x;
            asT[af * 4 + 1][r] = a.y;
            asT[af * 4 + 2][r] = a.z;
            asT[af * 4 + 3][r] = a.w;
        }
        {
            const float4* wp = (const float4*)&W[(long)k0 * HID];
            float4* bp = (float4*)bs;
#pragma unroll
            for (int i = 0; i < 4; i++) bp[t + i * 256] = wp[t + i * 256];
        }
        __syncthreads();
#pragma unroll 8
        for (int kk = 0; kk < KC; kk++) {
            const float4 a0 = *(const float4*)&asT[kk][ty * 8];
            const float4 a1 = *(const float4*)&asT[kk][ty * 8 + 4];
            const float4 b  = *(const float4*)&bs[kk * HID + tx * 4];
            acc[0].x = fmaf(a0.x, b.x, acc[0].x); acc[0].y = fmaf(a0.x, b.y, acc[0].y);
            acc[0].z = fmaf(a0.x, b.z, acc[0].z); acc[0].w = fmaf(a0.x, b.w, acc[0].w);
            acc[1].x = fmaf(a0.y, b.x, acc[1].x); acc[1].y = fmaf(a0.y, b.y, acc[1].y);
            acc[1].z = fmaf(a0.y, b.z, acc[1].z); acc[1].w = fmaf(a0.y, b.w, acc[1].w);
            acc[2].x = fmaf(a0.z, b.x, acc[2].x); acc[2].y = fmaf(a0.z, b.y, acc[2].y);
            acc[2].z = fmaf(a0.z, b.z, acc[2].z); acc[2].w = fmaf(a0.z, b.w, acc[2].w);
            acc[3].x = fmaf(a0.w, b.x, acc[3].x); acc[3].y = fmaf(a0.w, b.y, acc[3].y);
            acc[3].z = fmaf(a0.w, b.z, acc[3].z); acc[3].w = fmaf(a0.w, b.w, acc[3].w);
            acc[4].x = fmaf(a1.x, b.x, acc[4].x); acc[4].y = fmaf(a1.x, b.y, acc[4].y);
            acc[4].z = fmaf(a1.x, b.z, acc[4].z); acc[4].w = fmaf(a1.x, b.w, acc[4].w);
            acc[5].x = fmaf(a1.y, b.x, acc[5].x); acc[5].y = fmaf(a1.y, b.y, acc[5].y);
            acc[5].z = fmaf(a1.y, b.z, acc[5].z); acc[5].w = fmaf(a1.y, b.w, acc[5].w);
            acc[6].x = fmaf(a1.z, b.x, acc[6].x); acc[6].y = fmaf(a1.z, b.y, acc[6].y);
            acc[6].z = fmaf(a1.z, b.z, acc[6].z); acc[6].w = fmaf(a1.z, b.w, acc[6].w);
            acc[7].x = fmaf(a1.w, b.x, acc[7].x); acc[7].y = fmaf(a1.w, b.y, acc[7].y);
            acc[7].z = fmaf(a1.w, b.z, acc[7].z); acc[7].w = fmaf(a1.w, b.w, acc[7].w);
        }
        __syncthreads();
    }

#pragma unroll
    for (int j = 0; j < 8; j++) {
        const int v = row0 + ty * 8 + j;
        if (v < n) {
            const float s = dis[v] * 8.0f;   // x8 keeps layer-2 messages out of e4m3 subnormals
            int w01 = __builtin_amdgcn_cvt_pk_fp8_f32(acc[j].x * s, acc[j].y * s, 0, false);
            int w   = __builtin_amdgcn_cvt_pk_fp8_f32(acc[j].z * s, acc[j].w * s, w01, true);
            out8[(long)v * (HID / 4) + tx] = (unsigned int)w;
        }
    }
}

// ---------------- gather aggregation + finalize (+ optional fused pool) ----------------
// Proven round-0 structure (locally converged: FETCH at the 8xXCD*hs8 floor,
// 1 line/edge, ILP-insensitive). Inter-layer buffer stored as packed bf16.
template <bool POOL>
__global__ __launch_bounds__(256) void agg_kernel(const unsigned char* __restrict__ hs8,
                                                  const unsigned short* __restrict__ csr16,
                                                  const int* __restrict__ row,
                                                  const float* __restrict__ dis,
                                                  const float* __restrict__ bias,
                                                  const int* __restrict__ batch,
                                                  unsigned int* __restrict__ buf,   // bf16x2 packed
                                                  float* __restrict__ sums,
                                                  int* __restrict__ cnt, int n) {
    const int v = blockIdx.x * 4 + (threadIdx.x >> 6);
    if (v >= n) return;
    const int lane = threadIdx.x & 63;
    const int sub = lane >> 3;      // edge slot within pass (0..7)
    const int lc  = lane & 7;       // 16-byte chunk within row

    const int rs = row[v];
    const int re = row[v + 1];

    float acc[16];
#pragma unroll
    for (int i = 0; i < 16; i++) acc[i] = 0.f;

    for (int base = rs; base < re; base += 32) {
        uint4 w[4];
        int vld[4];
#pragma unroll
        for (int p = 0; p < 4; p++) {
            const int pe = base + p * 8;
            if (pe < re) {                       // wave-uniform guard
                const int ei = pe + sub;
                const int idx = __builtin_nontemporal_load(&csr16[(ei < re) ? ei : (re - 1)]);
                w[p] = *(const uint4*)&hs8[(long)idx * HID + (lc << 4)];
                vld[p] = (ei < re);
            } else {
                w[p] = make_uint4(0u, 0u, 0u, 0u);
                vld[p] = 0;
            }
        }
#pragma unroll
        for (int p = 0; p < 4; p++) {
            if (vld[p]) {
                const uint4 ww = w[p];
                f32x2 u;
                u = __builtin_amdgcn_cvt_pk_f32_fp8(ww.x, false); acc[0]  += u.x; acc[1]  += u.y;
                u = __builtin_amdgcn_cvt_pk_f32_fp8(ww.x, true);  acc[2]  += u.x; acc[3]  += u.y;
                u = __builtin_amdgcn_cvt_pk_f32_fp8(ww.y, false); acc[4]  += u.x; acc[5]  += u.y;
                u = __builtin_amdgcn_cvt_pk_f32_fp8(ww.y, true);  acc[6]  += u.x; acc[7]  += u.y;
                u = __builtin_amdgcn_cvt_pk_f32_fp8(ww.z, false); acc[8]  += u.x; acc[9]  += u.y;
                u = __builtin_amdgcn_cvt_pk_f32_fp8(ww.z, true);  acc[10] += u.x; acc[11] += u.y;
                u = __builtin_amdgcn_cvt_pk_f32_fp8(ww.w, false); acc[12] += u.x; acc[13] += u.y;
                u = __builtin_amdgcn_cvt_pk_f32_fp8(ww.w, true);  acc[14] += u.x; acc[15] += u.y;
            }
        }
    }

    // fold the 8 sub-groups (lanes differing in bits 3..5, same lc)
#pragma unroll
    for (int i = 0; i < 16; i++) {
        acc[i] += __shfl_xor(acc[i], 8, 64);
        acc[i] += __shfl_xor(acc[i], 16, 64);
        acc[i] += __shfl_xor(acc[i], 32, 64);
    }

    // each lane owns cols col, col+1 where col = 16*lc + 2*sub
    const int col = (lc << 4) + (sub << 1);
    const unsigned short selfw = *(const unsigned short*)&hs8[(long)v * HID + col];
    f32x2 sf = __builtin_amdgcn_cvt_pk_f32_fp8((unsigned int)selfw, false);
    const float sx = acc[(sub << 1) + 0] + sf.x;
    const float sy = acc[(sub << 1) + 1] + sf.y;
    const float dv = dis[v] * 0.125f;   // undo the x8 message scale
    const float rx = fmaxf(fmaf(dv, sx, bias[col]), 0.f);
    const float ry = fmaxf(fmaf(dv, sy, bias[col + 1]), 0.f);
    if (POOL) {
        const int g = batch[v];
        unsafeAtomicAdd(&sums[g * HID + col], rx);
        unsafeAtomicAdd(&sums[g * HID + col + 1], ry);
        if (lane == 0) atomicAdd(&cnt[g], 1);
    } else {
        const unsigned int pk = (unsigned int)f2bf(rx) | ((unsigned int)f2bf(ry) << 16);
        buf[(long)v * (HID / 2) + (col >> 1)] = pk;      // col is even
    }
}

// ---------------- mean + MLP head ----------------
__global__ __launch_bounds__(64) void mlp_kernel(const float* __restrict__ sums,
                                                 const int* __restrict__ cnt,
                                                 const float* __restrict__ Wl1,
                                                 const float* __restrict__ bl1,
                                                 const float* __restrict__ Wl2,
                                                 const float* __restrict__ bl2,
                                                 float* __restrict__ out) {
    const int g = blockIdx.x, t = threadIdx.x;
    __shared__ float mean[HID];
    __shared__ float hid[64];
    const float c = fmaxf((float)cnt[g], 1.0f);
    mean[t] = sums[g * HID + t] / c;
    mean[t + 64] = sums[g * HID + 64 + t] / c;
    __syncthreads();
    float acc = bl1[t];
#pragma unroll 4
    for (int k = 0; k < HID; k++) acc = fmaf(mean[k], Wl1[k * 64 + t], acc);
    hid[t] = fmaxf(acc, 0.f);
    __syncthreads();
    if (t < 5) {
        float a = bl2[t];
#pragma unroll 4
        for (int k = 0; k < 64; k++) a = fmaf(hid[k], Wl2[k * 5 + t], a);
        out[g * 5 + t] = 1.f / (1.f + expf(-a));
    }
}

extern "C" void kernel_launch(void* const* d_in, const int* in_sizes, int n_in,
                              void* d_out, int out_size, void* d_ws, size_t ws_size,
                              hipStream_t stream) {
    const float* x   = (const float*)d_in[0];
    const int* ei    = (const int*)d_in[1];
    const int* batch = (const int*)d_in[2];
    const float* W1  = (const float*)d_in[3];
    const float* b1  = (const float*)d_in[4];
    const float* W2  = (const float*)d_in[5];
    const float* b2  = (const float*)d_in[6];
    const float* Wl1 = (const float*)d_in[7];
    const float* bl1 = (const float*)d_in[8];
    const float* Wl2 = (const float*)d_in[9];
    const float* bl2 = (const float*)d_in[10];
    float* out = (float*)d_out;

    const int n = in_sizes[0] / IN_DIM;       // 50000
    const int E = in_sizes[1] / 2;            // 1600000
    const int* src = ei;
    const int* dst = ei + E;

    char* ws = (char*)d_ws;
    size_t off = 0;
    auto alloc = [&](size_t bytes) {
        void* p = ws + off;
        off = (off + bytes + 255) & ~(size_t)255;
        return p;
    };
    int*   deg       = (int*)alloc((size_t)n * 4);
    float* dis       = (float*)alloc((size_t)n * 4);
    int*   row       = (int*)alloc((size_t)(n + 1) * 4);
    int*   cursor    = (int*)alloc((size_t)n * 4);
    unsigned short* csr16 = (unsigned short*)alloc((size_t)E * 2);
    int*   blockSums = (int*)alloc(256 * 4);
    unsigned char* hs8 = (unsigned char*)alloc((size_t)n * HID);       // fp8 messages
    unsigned int* buf1 = (unsigned int*)alloc((size_t)n * HID * 2);    // bf16 inter-layer h
    float* sums = (float*)alloc((size_t)NGRAPH * HID * 4);             // 256-mult ->
    int*   cnt  = (int*)alloc((size_t)NGRAPH * 4);                     // contiguous with sums
    (void)ws_size;

    const int nb = (n + 1023) / 1024;
    const int gemmBlocks = (n + 63) / 64;
    const int aggBlocks  = (n + 3) / 4;
    const int edgeBlocks = (E + 255) / 256;

    // --- zero deg + (sums,cnt contiguous: one memset) ---
    hipMemsetAsync(deg, 0, (size_t)n * 4, stream);
    hipMemsetAsync(sums, 0, (size_t)NGRAPH * HID * 4 + (size_t)NGRAPH * 4, stream);

    // --- degree / norm / CSR (multi-block scan chain; R7 lesson) ---
    deg_kernel<<<edgeBlocks, 256, 0, stream>>>(dst, deg, E);
    dis_kernel<<<(n + 255) / 256, 256, 0, stream>>>(deg, dis, n);
    scan_part<<<nb, 256, 0, stream>>>(deg, row, blockSums, n);
    scan_tops<<<1, 64, 0, stream>>>(blockSums, nb);
    scan_add<<<nb, 256, 0, stream>>>(row, cursor, blockSums, n, E);
    // 4 dst-range sweeps keep csr16 writes L2-resident (low writeback amplification)
    {
        const int step = (n + 3) / 4;
        for (int k = 0; k < 4; k++) {
            const int lo = k * step;
            const int hi = (k == 3) ? n : (lo + step);
            fill_kernel<<<edgeBlocks, 256, 0, stream>>>(src, dst, cursor, csr16, E, lo, hi);
        }
    }

    // --- conv1 ---
    gemm_tile<IN_DIM, false><<<gemmBlocks, 256, 0, stream>>>(x, W1, dis, (unsigned int*)hs8, n);
    agg_kernel<false><<<aggBlocks, 256, 0, stream>>>(hs8, csr16, row, dis, b1, batch,
                                                     buf1, nullptr, nullptr, n);

    // --- conv2 (pool fused) ---
    gemm_tile<HID, true><<<gemmBlocks, 256, 0, stream>>>(buf1, W2, dis, (unsigned int*)hs8, n);
    agg_kernel<true><<<aggBlocks, 256, 0, stream>>>(hs8, csr16, row, dis, b2, batch,
                                                    nullptr, sums, cnt, n);

    // --- head ---
    mlp_kernel<<<NGRAPH, 64, 0, stream>>>(sums, cnt, Wl1, bl1, Wl2, bl2, out);
}

// Round 9
// 528.563 us; speedup vs baseline: 3.8107x; 1.1063x over previous
//
#include <hip/hip_runtime.h>
#include <hip/hip_bf16.h>
#include <string.h>

#define HID 128
#define NGRAPH 512
#define IN_DIM 384

typedef __attribute__((ext_vector_type(2))) float f32x2;
typedef __attribute__((ext_vector_type(4))) float f32x4;
typedef __attribute__((ext_vector_type(8))) short short8v;   // 8 bf16 = 4 VGPRs (guide §3)

__device__ __forceinline__ unsigned short f2bf(float f) {
    unsigned int b; __builtin_memcpy(&b, &f, 4);
    unsigned int r = (b + 0x7FFFu + ((b >> 16) & 1u)) >> 16;   // RNE
    return (unsigned short)r;
}

// ---------------- degree ----------------
__global__ void deg_kernel(const int* __restrict__ dst, int* __restrict__ deg, int E) {
    int e = blockIdx.x * blockDim.x + threadIdx.x;
    if (e < E) atomicAdd(&deg[dst[e]], 1);
}

// ---------------- W -> bf16 fragment pack (one-time, ~130 KB, L2-resident) ----------------
// Fragment order: [kc][nt][lane][j]  (j contiguous 16 B per lane), so the GEMM's
// B-frag load is one coalesced global_load_dwordx4 per lane.
// B layout (m89-verified family): col = nt*16 + (lane&15), k = kc*32 + (lane>>4)*8 + j.
__global__ __launch_bounds__(256) void pack_w(const float* __restrict__ W1,
                                              const float* __restrict__ W2,
                                              unsigned short* __restrict__ w8_1,
                                              unsigned short* __restrict__ w8_2) {
    const int f = blockIdx.x * 256 + threadIdx.x;
    const int F1 = (IN_DIM / 32) * 8 * 64;          // 6144
    const int F2 = (HID / 32) * 8 * 64;             // 2048
    if (f >= F1 + F2) return;
    const float* W = (f < F1) ? W1 : W2;
    unsigned short* o = (f < F1) ? w8_1 : w8_2;
    const int fl = (f < F1) ? f : (f - F1);
    const int kc = fl >> 9;
    const int nt = (fl >> 6) & 7;
    const int l  = fl & 63;
    const int kb = kc * 32 + ((l >> 4) << 3);
    const int col = nt * 16 + (l & 15);
    unsigned int u0 = (unsigned int)f2bf(W[(long)(kb + 0) * HID + col]) |
                      ((unsigned int)f2bf(W[(long)(kb + 1) * HID + col]) << 16);
    unsigned int u1 = (unsigned int)f2bf(W[(long)(kb + 2) * HID + col]) |
                      ((unsigned int)f2bf(W[(long)(kb + 3) * HID + col]) << 16);
    unsigned int u2 = (unsigned int)f2bf(W[(long)(kb + 4) * HID + col]) |
                      ((unsigned int)f2bf(W[(long)(kb + 5) * HID + col]) << 16);
    unsigned int u3 = (unsigned int)f2bf(W[(long)(kb + 6) * HID + col]) |
                      ((unsigned int)f2bf(W[(long)(kb + 7) * HID + col]) << 16);
    *(uint4*)&o[(size_t)fl * 8] = make_uint4(u0, u1, u2, u3);
}

// ---------------- exclusive scan of deg -> row_start (+ dis fused; multi-block) ----------------
__global__ __launch_bounds__(256) void scan_part(const int* __restrict__ deg, int* __restrict__ row,
                                                 int* __restrict__ blockSums, float* __restrict__ dis,
                                                 int n) {
    __shared__ int ts[256];
    const int b = blockIdx.x, t = threadIdx.x;
    const int base = b * 1024 + t * 4;
    int v0 = (base + 0 < n) ? deg[base + 0] : 0;
    int v1 = (base + 1 < n) ? deg[base + 1] : 0;
    int v2 = (base + 2 < n) ? deg[base + 2] : 0;
    int v3 = (base + 3 < n) ? deg[base + 3] : 0;
    // dis fused here: deg values are already in registers (saves a launch + re-read)
    if (base + 0 < n) dis[base + 0] = rsqrtf((float)(v0 + 1));
    if (base + 1 < n) dis[base + 1] = rsqrtf((float)(v1 + 1));
    if (base + 2 < n) dis[base + 2] = rsqrtf((float)(v2 + 1));
    if (base + 3 < n) dis[base + 3] = rsqrtf((float)(v3 + 1));
    const int s = v0 + v1 + v2 + v3;
    ts[t] = s;
    __syncthreads();
    for (int off = 1; off < 256; off <<= 1) {
        int x = (t >= off) ? ts[t - off] : 0;
        __syncthreads();
        ts[t] += x;
        __syncthreads();
    }
    int p = ts[t] - s;
    if (base + 0 < n) { row[base + 0] = p; p += v0; }
    if (base + 1 < n) { row[base + 1] = p; p += v1; }
    if (base + 2 < n) { row[base + 2] = p; p += v2; }
    if (base + 3 < n) { row[base + 3] = p; }
    if (t == 255) blockSums[b] = ts[255];
}

__global__ void scan_tops(int* __restrict__ blockSums, int nb) {
    if (threadIdx.x == 0 && blockIdx.x == 0) {
        int acc = 0;
        for (int i = 0; i < nb; i++) { int v = blockSums[i]; blockSums[i] = acc; acc += v; }
    }
}

__global__ __launch_bounds__(256) void scan_add(int* __restrict__ row, int* __restrict__ cursor,
                                                const int* __restrict__ blockSums, int n, int E) {
    const int b = blockIdx.x, t = threadIdx.x;
    const int off = blockSums[b];
    const int base = b * 1024 + t * 4;
#pragma unroll
    for (int j = 0; j < 4; j++) {
        int i = base + j;
        if (i < n) { int v = row[i] + off; row[i] = v; cursor[i] = v; }
    }
    if (b == 0 && t == 0) row[n] = E;
}

// ---------------- CSR fill (ushort src ids, dst-range sweep; lean, no LDS) ----------------
__global__ void fill_kernel(const int* __restrict__ src, const int* __restrict__ dst,
                            int* __restrict__ cursor, unsigned short* __restrict__ csr16,
                            int E, int lo, int hi) {
    int e = blockIdx.x * blockDim.x + threadIdx.x;
    if (e < E) {
        const int d = dst[e];
        if (d >= lo && d < hi) {
            int pos = atomicAdd(&cursor[d], 1);
            csr16[pos] = (unsigned short)src[e];
        }
    }
}

// ---- MFMA GEMM: hs8[v,:] = fp8_e4m3( (X[v,:] @ W) * dis[v] * 8 ) ----
// bf16 MFMA (2.5 PF) replaces the fp32 vector path (157 TF). Numerics: layer-2 input
// is already bf16 (buf1) -> identical precision; layer-1 adds bf16 rounding on x/W1,
// ~15x below the fp8 message quantization applied to the output.
// Tile: 64 rows x 128 cols, 4 waves (wave = 16 rows), K chunked by 32.
// A staged in LDS as bf16 [64][32] with 16B-block XOR swizzle (~2-way banks).
// Layouts (m89-verified family): A row=lane&15, k=8*(lane>>4)+j; B col=lane&15;
// D col=lane&15, row=4*(lane>>4)+reg. Epilogue round-trips via LDS to reuse the
// proven fp8 packing code verbatim.
template <int K, bool BF16IN>
__global__ __launch_bounds__(256) void gemm_mfma(const void* __restrict__ Xv,
                                                 const unsigned short* __restrict__ w8,
                                                 const float* __restrict__ dis,
                                                 unsigned int* __restrict__ out8, int n) {
    __shared__ __align__(16) unsigned char smem[64 * 132 * 4];   // 33792 B (union: A-stage / epilogue)
    float* eps = (float*)smem;                                   // [64][132] f32 after K loop

    const int t = threadIdx.x;
    const int lane = t & 63;
    const int wave = t >> 6;
    const int row0 = blockIdx.x * 64;

    f32x4 acc[8];
#pragma unroll
    for (int i = 0; i < 8; i++) acc[i] = (f32x4){0.f, 0.f, 0.f, 0.f};

    // staging coords: thread t -> row sr, k-chunk sq (8 bf16 = 16 B)
    const int sr = t >> 2;
    const int sq = t & 3;
    const int sw_byte = ((sr * 64 + sq * 16) ^ ((sr & 7) << 4));          // write addr
    // A-frag read coords for this lane
    const int am = (wave << 4) + (lane & 15);
    const int ac = lane >> 4;
    const int ard_byte = ((am * 64 + ac * 16) ^ ((am & 7) << 4));         // read addr

    const int nsteps = K / 32;
    for (int ks = 0; ks < nsteps; ++ks) {
        const int k0 = ks * 32;
        {   // stage A tile (64x32) as bf16
            const int gr = row0 + sr;
            unsigned int u0 = 0, u1 = 0, u2 = 0, u3 = 0;
            if (gr < n) {
                if constexpr (BF16IN) {
                    const uint4 b = *(const uint4*)((const unsigned short*)Xv + (size_t)gr * K + k0 + sq * 8);
                    u0 = b.x; u1 = b.y; u2 = b.z; u3 = b.w;
                } else {
                    const float4 x0 = *(const float4*)((const float*)Xv + (size_t)gr * K + k0 + sq * 8);
                    const float4 x1 = *(const float4*)((const float*)Xv + (size_t)gr * K + k0 + sq * 8 + 4);
                    u0 = (unsigned int)f2bf(x0.x) | ((unsigned int)f2bf(x0.y) << 16);
                    u1 = (unsigned int)f2bf(x0.z) | ((unsigned int)f2bf(x0.w) << 16);
                    u2 = (unsigned int)f2bf(x1.x) | ((unsigned int)f2bf(x1.y) << 16);
                    u3 = (unsigned int)f2bf(x1.z) | ((unsigned int)f2bf(x1.w) << 16);
                }
            }
            *(uint4*)(smem + sw_byte) = make_uint4(u0, u1, u2, u3);
        }
        __syncthreads();
        {   // compute: 1 A-frag ds_read_b128 + 8 (B-frag L2 load + MFMA)
            const short8v a = *(const short8v*)(smem + ard_byte);
            const unsigned short* wp = w8 + ((size_t)(ks * 8) * 64 + lane) * 8;
#pragma unroll
            for (int nt = 0; nt < 8; ++nt) {
                const short8v b = *(const short8v*)(wp + (size_t)nt * 64 * 8);
                acc[nt] = __builtin_amdgcn_mfma_f32_16x16x32_bf16(a, b, acc[nt], 0, 0, 0);
            }
        }
        __syncthreads();
    }

    // scatter acc -> eps (D layout: row = m0+4*(lane>>4)+reg, col = nt*16+(lane&15))
    {
        const int er = (wave << 4) + ((lane >> 4) << 2);
        const int ec = lane & 15;
#pragma unroll
        for (int nt = 0; nt < 8; ++nt) {
#pragma unroll
            for (int r = 0; r < 4; ++r) {
                eps[(size_t)(er + r) * 132 + nt * 16 + ec] = acc[nt][r];
            }
        }
    }
    __syncthreads();
    // proven fp8 packing epilogue (identical numerics to the old gemm_tile)
    {
        const int tx = t & 31;
        const int ty = t >> 5;
#pragma unroll
        for (int j = 0; j < 8; ++j) {
            const int v = row0 + ty * 8 + j;
            if (v < n) {
                const float4 a4 = *(const float4*)&eps[(size_t)(ty * 8 + j) * 132 + tx * 4];
                const float s = dis[v] * 8.0f;   // x8 keeps layer-2 messages out of e4m3 subnormals
                int w01 = __builtin_amdgcn_cvt_pk_fp8_f32(a4.x * s, a4.y * s, 0, false);
                int w   = __builtin_amdgcn_cvt_pk_fp8_f32(a4.z * s, a4.w * s, w01, true);
                out8[(size_t)v * (HID / 4) + tx] = (unsigned int)w;
            }
        }
    }
}

// ---------------- gather aggregation + finalize (+ optional fused pool) ----------------
// Proven round-0 structure (locally converged: FETCH at the 8xXCD*hs8 floor,
// 1 line/edge, ILP-insensitive). Inter-layer buffer stored as packed bf16.
template <bool POOL>
__global__ __launch_bounds__(256) void agg_kernel(const unsigned char* __restrict__ hs8,
                                                  const unsigned short* __restrict__ csr16,
                                                  const int* __restrict__ row,
                                                  const float* __restrict__ dis,
                                                  const float* __restrict__ bias,
                                                  const int* __restrict__ batch,
                                                  unsigned int* __restrict__ buf,   // bf16x2 packed
                                                  float* __restrict__ sums,
                                                  int* __restrict__ cnt, int n) {
    const int v = blockIdx.x * 4 + (threadIdx.x >> 6);
    if (v >= n) return;
    const int lane = threadIdx.x & 63;
    const int sub = lane >> 3;      // edge slot within pass (0..7)
    const int lc  = lane & 7;       // 16-byte chunk within row

    const int rs = row[v];
    const int re = row[v + 1];

    float acc[16];
#pragma unroll
    for (int i = 0; i < 16; i++) acc[i] = 0.f;

    for (int base = rs; base < re; base += 32) {
        uint4 w[4];
        int vld[4];
#pragma unroll
        for (int p = 0; p < 4; p++) {
            const int pe = base + p * 8;
            if (pe < re) {                       // wave-uniform guard
                const int ei = pe + sub;
                const int idx = __builtin_nontemporal_load(&csr16[(ei < re) ? ei : (re - 1)]);
                w[p] = *(const uint4*)&hs8[(long)idx * HID + (lc << 4)];
                vld[p] = (ei < re);
            } else {
                w[p] = make_uint4(0u, 0u, 0u, 0u);
                vld[p] = 0;
            }
        }
#pragma unroll
        for (int p = 0; p < 4; p++) {
            if (vld[p]) {
                const uint4 ww = w[p];
                f32x2 u;
                u = __builtin_amdgcn_cvt_pk_f32_fp8(ww.x, false); acc[0]  += u.x; acc[1]  += u.y;
                u = __builtin_amdgcn_cvt_pk_f32_fp8(ww.x, true);  acc[2]  += u.x; acc[3]  += u.y;
                u = __builtin_amdgcn_cvt_pk_f32_fp8(ww.y, false); acc[4]  += u.x; acc[5]  += u.y;
                u = __builtin_amdgcn_cvt_pk_f32_fp8(ww.y, true);  acc[6]  += u.x; acc[7]  += u.y;
                u = __builtin_amdgcn_cvt_pk_f32_fp8(ww.z, false); acc[8]  += u.x; acc[9]  += u.y;
                u = __builtin_amdgcn_cvt_pk_f32_fp8(ww.z, true);  acc[10] += u.x; acc[11] += u.y;
                u = __builtin_amdgcn_cvt_pk_f32_fp8(ww.w, false); acc[12] += u.x; acc[13] += u.y;
                u = __builtin_amdgcn_cvt_pk_f32_fp8(ww.w, true);  acc[14] += u.x; acc[15] += u.y;
            }
        }
    }

    // fold the 8 sub-groups (lanes differing in bits 3..5, same lc)
#pragma unroll
    for (int i = 0; i < 16; i++) {
        acc[i] += __shfl_xor(acc[i], 8, 64);
        acc[i] += __shfl_xor(acc[i], 16, 64);
        acc[i] += __shfl_xor(acc[i], 32, 64);
    }

    // each lane owns cols col, col+1 where col = 16*lc + 2*sub
    const int col = (lc << 4) + (sub << 1);
    const unsigned short selfw = *(const unsigned short*)&hs8[(long)v * HID + col];
    f32x2 sf = __builtin_amdgcn_cvt_pk_f32_fp8((unsigned int)selfw, false);
    const float sx = acc[(sub << 1) + 0] + sf.x;
    const float sy = acc[(sub << 1) + 1] + sf.y;
    const float dv = dis[v] * 0.125f;   // undo the x8 message scale
    const float rx = fmaxf(fmaf(dv, sx, bias[col]), 0.f);
    const float ry = fmaxf(fmaf(dv, sy, bias[col + 1]), 0.f);
    if (POOL) {
        const int g = batch[v];
        unsafeAtomicAdd(&sums[g * HID + col], rx);
        unsafeAtomicAdd(&sums[g * HID + col + 1], ry);
        if (lane == 0) atomicAdd(&cnt[g], 1);
    } else {
        const unsigned int pk = (unsigned int)f2bf(rx) | ((unsigned int)f2bf(ry) << 16);
        buf[(long)v * (HID / 2) + (col >> 1)] = pk;      // col is even
    }
}

// ---------------- mean + MLP head ----------------
__global__ __launch_bounds__(64) void mlp_kernel(const float* __restrict__ sums,
                                                 const int* __restrict__ cnt,
                                                 const float* __restrict__ Wl1,
                                                 const float* __restrict__ bl1,
                                                 const float* __restrict__ Wl2,
                                                 const float* __restrict__ bl2,
                                                 float* __restrict__ out) {
    const int g = blockIdx.x, t = threadIdx.x;
    __shared__ float mean[HID];
    __shared__ float hid[64];
    const float c = fmaxf((float)cnt[g], 1.0f);
    mean[t] = sums[g * HID + t] / c;
    mean[t + 64] = sums[g * HID + 64 + t] / c;
    __syncthreads();
    float acc = bl1[t];
#pragma unroll 4
    for (int k = 0; k < HID; k++) acc = fmaf(mean[k], Wl1[k * 64 + t], acc);
    hid[t] = fmaxf(acc, 0.f);
    __syncthreads();
    if (t < 5) {
        float a = bl2[t];
#pragma unroll 4
        for (int k = 0; k < 64; k++) a = fmaf(hid[k], Wl2[k * 5 + t], a);
        out[g * 5 + t] = 1.f / (1.f + expf(-a));
    }
}

extern "C" void kernel_launch(void* const* d_in, const int* in_sizes, int n_in,
                              void* d_out, int out_size, void* d_ws, size_t ws_size,
                              hipStream_t stream) {
    const float* x   = (const float*)d_in[0];
    const int* ei    = (const int*)d_in[1];
    const int* batch = (const int*)d_in[2];
    const float* W1  = (const float*)d_in[3];
    const float* b1  = (const float*)d_in[4];
    const float* W2  = (const float*)d_in[5];
    const float* b2  = (const float*)d_in[6];
    const float* Wl1 = (const float*)d_in[7];
    const float* bl1 = (const float*)d_in[8];
    const float* Wl2 = (const float*)d_in[9];
    const float* bl2 = (const float*)d_in[10];
    float* out = (float*)d_out;

    const int n = in_sizes[0] / IN_DIM;       // 50000
    const int E = in_sizes[1] / 2;            // 1600000
    const int* src = ei;
    const int* dst = ei + E;

    char* ws = (char*)d_ws;
    size_t off = 0;
    auto alloc = [&](size_t bytes) {
        void* p = ws + off;
        off = (off + bytes + 255) & ~(size_t)255;
        return p;
    };
    int*   deg       = (int*)alloc((size_t)n * 4);
    float* dis       = (float*)alloc((size_t)n * 4);
    int*   row       = (int*)alloc((size_t)(n + 1) * 4);
    int*   cursor    = (int*)alloc((size_t)n * 4);
    unsigned short* csr16 = (unsigned short*)alloc((size_t)E * 2);
    int*   blockSums = (int*)alloc(256 * 4);
    unsigned char* hs8 = (unsigned char*)alloc((size_t)n * HID);       // fp8 messages
    unsigned int* buf1 = (unsigned int*)alloc((size_t)n * HID * 2);    // bf16 inter-layer h
    unsigned short* w8_1 = (unsigned short*)alloc((size_t)IN_DIM * HID * 2);  // W1 bf16 frags
    unsigned short* w8_2 = (unsigned short*)alloc((size_t)HID * HID * 2);     // W2 bf16 frags
    float* sums = (float*)alloc((size_t)NGRAPH * HID * 4);             // 256-mult ->
    int*   cnt  = (int*)alloc((size_t)NGRAPH * 4);                     // contiguous with sums
    (void)ws_size;

    const int nb = (n + 1023) / 1024;
    const int gemmBlocks = (n + 63) / 64;
    const int aggBlocks  = (n + 3) / 4;
    const int edgeBlocks = (E + 255) / 256;

    // --- zero deg + (sums,cnt contiguous: one memset) ---
    hipMemsetAsync(deg, 0, (size_t)n * 4, stream);
    hipMemsetAsync(sums, 0, (size_t)NGRAPH * HID * 4 + (size_t)NGRAPH * 4, stream);

    // --- pack W1/W2 into bf16 MFMA fragment order (one-time) ---
    pack_w<<<32, 256, 0, stream>>>(W1, W2, w8_1, w8_2);

    // --- degree / norm / CSR (multi-block scan chain; dis fused into scan_part) ---
    deg_kernel<<<edgeBlocks, 256, 0, stream>>>(dst, deg, E);
    scan_part<<<nb, 256, 0, stream>>>(deg, row, blockSums, dis, n);
    scan_tops<<<1, 64, 0, stream>>>(blockSums, nb);
    scan_add<<<nb, 256, 0, stream>>>(row, cursor, blockSums, n, E);
    // 4 dst-range sweeps keep csr16 writes L2-resident (low writeback amplification)
    {
        const int step = (n + 3) / 4;
        for (int k = 0; k < 4; k++) {
            const int lo = k * step;
            const int hi = (k == 3) ? n : (lo + step);
            fill_kernel<<<edgeBlocks, 256, 0, stream>>>(src, dst, cursor, csr16, E, lo, hi);
        }
    }

    // --- conv1 (bf16 MFMA) ---
    gemm_mfma<IN_DIM, false><<<gemmBlocks, 256, 0, stream>>>(x, w8_1, dis, (unsigned int*)hs8, n);
    agg_kernel<false><<<aggBlocks, 256, 0, stream>>>(hs8, csr16, row, dis, b1, batch,
                                                     buf1, nullptr, nullptr, n);

    // --- conv2 (bf16 MFMA; pool fused in agg) ---
    gemm_mfma<HID, true><<<gemmBlocks, 256, 0, stream>>>(buf1, w8_2, dis, (unsigned int*)hs8, n);
    agg_kernel<true><<<aggBlocks, 256, 0, stream>>>(hs8, csr16, row, dis, b2, batch,
                                                    nullptr, sums, cnt, n);

    // --- head ---
    mlp_kernel<<<NGRAPH, 64, 0, stream>>>(sums, cnt, Wl1, bl1, Wl2, bl2, out);
}

// Round 10
// 514.269 us; speedup vs baseline: 3.9167x; 1.0278x over previous
//
#include <hip/hip_runtime.h>
#include <hip/hip_bf16.h>
#include <string.h>

#define HID 128
#define NGRAPH 512
#define IN_DIM 384

typedef __attribute__((ext_vector_type(2))) float f32x2;
typedef __attribute__((ext_vector_type(4))) float f32x4;
typedef __attribute__((ext_vector_type(8))) short short8v;   // 8 bf16 = 4 VGPRs (guide §3)

__device__ __forceinline__ unsigned short f2bf(float f) {
    unsigned int b; __builtin_memcpy(&b, &f, 4);
    unsigned int r = (b + 0x7FFFu + ((b >> 16) & 1u)) >> 16;   // RNE
    return (unsigned short)r;
}

// ---------------- degree (int2-vectorized: 2 edges/thread) ----------------
__global__ void deg_kernel(const int* __restrict__ dst, int* __restrict__ deg, int E) {
    const int e0 = (blockIdx.x * blockDim.x + threadIdx.x) * 2;
    if (e0 + 1 < E) {
        const int2 d2 = *(const int2*)&dst[e0];
        atomicAdd(&deg[d2.x], 1);
        atomicAdd(&deg[d2.y], 1);
    } else if (e0 < E) {
        atomicAdd(&deg[dst[e0]], 1);
    }
}

// ---------------- W -> bf16 fragment pack (one-time, ~130 KB, L2-resident) ----------------
// B layout (m89-verified family): col = nt*16 + (lane&15), k = kc*32 + (lane>>4)*8 + j.
__global__ __launch_bounds__(256) void pack_w(const float* __restrict__ W1,
                                              const float* __restrict__ W2,
                                              unsigned short* __restrict__ w8_1,
                                              unsigned short* __restrict__ w8_2) {
    const int f = blockIdx.x * 256 + threadIdx.x;
    const int F1 = (IN_DIM / 32) * 8 * 64;          // 6144
    const int F2 = (HID / 32) * 8 * 64;             // 2048
    if (f >= F1 + F2) return;
    const float* W = (f < F1) ? W1 : W2;
    unsigned short* o = (f < F1) ? w8_1 : w8_2;
    const int fl = (f < F1) ? f : (f - F1);
    const int kc = fl >> 9;
    const int nt = (fl >> 6) & 7;
    const int l  = fl & 63;
    const int kb = kc * 32 + ((l >> 4) << 3);
    const int col = nt * 16 + (l & 15);
    unsigned int u0 = (unsigned int)f2bf(W[(long)(kb + 0) * HID + col]) |
                      ((unsigned int)f2bf(W[(long)(kb + 1) * HID + col]) << 16);
    unsigned int u1 = (unsigned int)f2bf(W[(long)(kb + 2) * HID + col]) |
                      ((unsigned int)f2bf(W[(long)(kb + 3) * HID + col]) << 16);
    unsigned int u2 = (unsigned int)f2bf(W[(long)(kb + 4) * HID + col]) |
                      ((unsigned int)f2bf(W[(long)(kb + 5) * HID + col]) << 16);
    unsigned int u3 = (unsigned int)f2bf(W[(long)(kb + 6) * HID + col]) |
                      ((unsigned int)f2bf(W[(long)(kb + 7) * HID + col]) << 16);
    *(uint4*)&o[(size_t)fl * 8] = make_uint4(u0, u1, u2, u3);
}

// ---------------- exclusive scan of deg -> row_start (+ dis fused; multi-block) ----------------
__global__ __launch_bounds__(256) void scan_part(const int* __restrict__ deg, int* __restrict__ row,
                                                 int* __restrict__ blockSums, float* __restrict__ dis,
                                                 int n) {
    __shared__ int ts[256];
    const int b = blockIdx.x, t = threadIdx.x;
    const int base = b * 1024 + t * 4;
    int v0 = (base + 0 < n) ? deg[base + 0] : 0;
    int v1 = (base + 1 < n) ? deg[base + 1] : 0;
    int v2 = (base + 2 < n) ? deg[base + 2] : 0;
    int v3 = (base + 3 < n) ? deg[base + 3] : 0;
    if (base + 0 < n) dis[base + 0] = rsqrtf((float)(v0 + 1));
    if (base + 1 < n) dis[base + 1] = rsqrtf((float)(v1 + 1));
    if (base + 2 < n) dis[base + 2] = rsqrtf((float)(v2 + 1));
    if (base + 3 < n) dis[base + 3] = rsqrtf((float)(v3 + 1));
    const int s = v0 + v1 + v2 + v3;
    ts[t] = s;
    __syncthreads();
    for (int off = 1; off < 256; off <<= 1) {
        int x = (t >= off) ? ts[t - off] : 0;
        __syncthreads();
        ts[t] += x;
        __syncthreads();
    }
    int p = ts[t] - s;
    if (base + 0 < n) { row[base + 0] = p; p += v0; }
    if (base + 1 < n) { row[base + 1] = p; p += v1; }
    if (base + 2 < n) { row[base + 2] = p; p += v2; }
    if (base + 3 < n) { row[base + 3] = p; }
    if (t == 255) blockSums[b] = ts[255];
}

__global__ void scan_tops(int* __restrict__ blockSums, int nb) {
    if (threadIdx.x == 0 && blockIdx.x == 0) {
        int acc = 0;
        for (int i = 0; i < nb; i++) { int v = blockSums[i]; blockSums[i] = acc; acc += v; }
    }
}

__global__ __launch_bounds__(256) void scan_add(int* __restrict__ row, int* __restrict__ cursor,
                                                const int* __restrict__ blockSums, int n, int E) {
    const int b = blockIdx.x, t = threadIdx.x;
    const int off = blockSums[b];
    const int base = b * 1024 + t * 4;
#pragma unroll
    for (int j = 0; j < 4; j++) {
        int i = base + j;
        if (i < n) { int v = row[i] + off; row[i] = v; cursor[i] = v; }
    }
    if (b == 0 && t == 0) row[n] = E;
}

// ---------------- CSR fill (ushort src ids, dst-range sweep; int2-vectorized) ----------------
// 2 sweeps (was 4): active csr16 region 1.6 MB — still << 4 MB/XCD L2, two fewer
// full dst scans. Intra-row fill order changes -> fp32 sum reorder only (absmax
// headroom 5x; identical reorders passed in R3).
__global__ void fill_kernel(const int* __restrict__ src, const int* __restrict__ dst,
                            int* __restrict__ cursor, unsigned short* __restrict__ csr16,
                            int E, int lo, int hi) {
    const int e0 = (blockIdx.x * blockDim.x + threadIdx.x) * 2;
    if (e0 + 1 < E) {
        const int2 d2 = *(const int2*)&dst[e0];
        if (d2.x >= lo && d2.x < hi) {
            int pos = atomicAdd(&cursor[d2.x], 1);
            csr16[pos] = (unsigned short)src[e0];
        }
        if (d2.y >= lo && d2.y < hi) {
            int pos = atomicAdd(&cursor[d2.y], 1);
            csr16[pos] = (unsigned short)src[e0 + 1];
        }
    } else if (e0 < E) {
        const int d = dst[e0];
        if (d >= lo && d < hi) {
            int pos = atomicAdd(&cursor[d], 1);
            csr16[pos] = (unsigned short)src[e0];
        }
    }
}

// ---- MFMA GEMM: hs8[v,:] = fp8_e4m3( (X[v,:] @ W) * dis[v] * 8 ) ----
// bf16 MFMA (2.5 PF) replaces the fp32 vector path. Verified WIN in R9 (-56 us).
// Tile: 64 rows x 128 cols, 4 waves (wave = 16 rows), K chunked by 32.
// A staged in LDS as bf16 [64][32] with 16B-block XOR swizzle (~2-way banks).
template <int K, bool BF16IN>
__global__ __launch_bounds__(256) void gemm_mfma(const void* __restrict__ Xv,
                                                 const unsigned short* __restrict__ w8,
                                                 const float* __restrict__ dis,
                                                 unsigned int* __restrict__ out8, int n) {
    __shared__ __align__(16) unsigned char smem[64 * 132 * 4];   // union: A-stage / epilogue
    float* eps = (float*)smem;                                   // [64][132] f32 after K loop

    const int t = threadIdx.x;
    const int lane = t & 63;
    const int wave = t >> 6;
    const int row0 = blockIdx.x * 64;

    f32x4 acc[8];
#pragma unroll
    for (int i = 0; i < 8; i++) acc[i] = (f32x4){0.f, 0.f, 0.f, 0.f};

    const int sr = t >> 2;
    const int sq = t & 3;
    const int sw_byte = ((sr * 64 + sq * 16) ^ ((sr & 7) << 4));          // write addr
    const int am = (wave << 4) + (lane & 15);
    const int ac = lane >> 4;
    const int ard_byte = ((am * 64 + ac * 16) ^ ((am & 7) << 4));         // read addr

    const int nsteps = K / 32;
    for (int ks = 0; ks < nsteps; ++ks) {
        const int k0 = ks * 32;
        {   // stage A tile (64x32) as bf16
            const int gr = row0 + sr;
            unsigned int u0 = 0, u1 = 0, u2 = 0, u3 = 0;
            if (gr < n) {
                if constexpr (BF16IN) {
                    const uint4 b = *(const uint4*)((const unsigned short*)Xv + (size_t)gr * K + k0 + sq * 8);
                    u0 = b.x; u1 = b.y; u2 = b.z; u3 = b.w;
                } else {
                    const float4 x0 = *(const float4*)((const float*)Xv + (size_t)gr * K + k0 + sq * 8);
                    const float4 x1 = *(const float4*)((const float*)Xv + (size_t)gr * K + k0 + sq * 8 + 4);
                    u0 = (unsigned int)f2bf(x0.x) | ((unsigned int)f2bf(x0.y) << 16);
                    u1 = (unsigned int)f2bf(x0.z) | ((unsigned int)f2bf(x0.w) << 16);
                    u2 = (unsigned int)f2bf(x1.x) | ((unsigned int)f2bf(x1.y) << 16);
                    u3 = (unsigned int)f2bf(x1.z) | ((unsigned int)f2bf(x1.w) << 16);
                }
            }
            *(uint4*)(smem + sw_byte) = make_uint4(u0, u1, u2, u3);
        }
        __syncthreads();
        {   // compute: 1 A-frag ds_read_b128 + 8 (B-frag L2 load + MFMA)
            const short8v a = *(const short8v*)(smem + ard_byte);
            const unsigned short* wp = w8 + ((size_t)(ks * 8) * 64 + lane) * 8;
#pragma unroll
            for (int nt = 0; nt < 8; ++nt) {
                const short8v b = *(const short8v*)(wp + (size_t)nt * 64 * 8);
                acc[nt] = __builtin_amdgcn_mfma_f32_16x16x32_bf16(a, b, acc[nt], 0, 0, 0);
            }
        }
        __syncthreads();
    }

    // scatter acc -> eps (D layout: row = m0+4*(lane>>4)+reg, col = nt*16+(lane&15))
    {
        const int er = (wave << 4) + ((lane >> 4) << 2);
        const int ec = lane & 15;
#pragma unroll
        for (int nt = 0; nt < 8; ++nt) {
#pragma unroll
            for (int r = 0; r < 4; ++r) {
                eps[(size_t)(er + r) * 132 + nt * 16 + ec] = acc[nt][r];
            }
        }
    }
    __syncthreads();
    // proven fp8 packing epilogue (identical numerics to the old gemm_tile)
    {
        const int tx = t & 31;
        const int ty = t >> 5;
#pragma unroll
        for (int j = 0; j < 8; ++j) {
            const int v = row0 + ty * 8 + j;
            if (v < n) {
                const float4 a4 = *(const float4*)&eps[(size_t)(ty * 8 + j) * 132 + tx * 4];
                const float s = dis[v] * 8.0f;   // x8 keeps layer-2 messages out of e4m3 subnormals
                int w01 = __builtin_amdgcn_cvt_pk_fp8_f32(a4.x * s, a4.y * s, 0, false);
                int w   = __builtin_amdgcn_cvt_pk_fp8_f32(a4.z * s, a4.w * s, w01, true);
                out8[(size_t)v * (HID / 4) + tx] = (unsigned int)w;
            }
        }
    }
}

// ---------------- gather aggregation + finalize (+ optional fused pool) ----------------
// Structural floor: FETCH = compulsory 8xXCD pass of hs8 (6.4 MB > 4 MB L2);
// time set by per-XCD L2->L3 miss-queue occupancy. ILP-insensitive (R1),
// bytes-proportional (R3). Do not touch.
template <bool POOL>
__global__ __launch_bounds__(256) void agg_kernel(const unsigned char* __restrict__ hs8,
                                                  const unsigned short* __restrict__ csr16,
                                                  const int* __restrict__ row,
                                                  const float* __restrict__ dis,
                                                  const float* __restrict__ bias,
                                                  const int* __restrict__ batch,
                                                  unsigned int* __restrict__ buf,   // bf16x2 packed
                                                  float* __restrict__ sums,
                                                  int* __restrict__ cnt, int n) {
    const int v = blockIdx.x * 4 + (threadIdx.x >> 6);
    if (v >= n) return;
    const int lane = threadIdx.x & 63;
    const int sub = lane >> 3;      // edge slot within pass (0..7)
    const int lc  = lane & 7;       // 16-byte chunk within row

    const int rs = row[v];
    const int re = row[v + 1];

    float acc[16];
#pragma unroll
    for (int i = 0; i < 16; i++) acc[i] = 0.f;

    for (int base = rs; base < re; base += 32) {
        uint4 w[4];
        int vld[4];
#pragma unroll
        for (int p = 0; p < 4; p++) {
            const int pe = base + p * 8;
            if (pe < re) {                       // wave-uniform guard
                const int ei = pe + sub;
                const int idx = __builtin_nontemporal_load(&csr16[(ei < re) ? ei : (re - 1)]);
                w[p] = *(const uint4*)&hs8[(long)idx * HID + (lc << 4)];
                vld[p] = (ei < re);
            } else {
                w[p] = make_uint4(0u, 0u, 0u, 0u);
                vld[p] = 0;
            }
        }
#pragma unroll
        for (int p = 0; p < 4; p++) {
            if (vld[p]) {
                const uint4 ww = w[p];
                f32x2 u;
                u = __builtin_amdgcn_cvt_pk_f32_fp8(ww.x, false); acc[0]  += u.x; acc[1]  += u.y;
                u = __builtin_amdgcn_cvt_pk_f32_fp8(ww.x, true);  acc[2]  += u.x; acc[3]  += u.y;
                u = __builtin_amdgcn_cvt_pk_f32_fp8(ww.y, false); acc[4]  += u.x; acc[5]  += u.y;
                u = __builtin_amdgcn_cvt_pk_f32_fp8(ww.y, true);  acc[6]  += u.x; acc[7]  += u.y;
                u = __builtin_amdgcn_cvt_pk_f32_fp8(ww.z, false); acc[8]  += u.x; acc[9]  += u.y;
                u = __builtin_amdgcn_cvt_pk_f32_fp8(ww.z, true);  acc[10] += u.x; acc[11] += u.y;
                u = __builtin_amdgcn_cvt_pk_f32_fp8(ww.w, false); acc[12] += u.x; acc[13] += u.y;
                u = __builtin_amdgcn_cvt_pk_f32_fp8(ww.w, true);  acc[14] += u.x; acc[15] += u.y;
            }
        }
    }

    // fold the 8 sub-groups (lanes differing in bits 3..5, same lc)
#pragma unroll
    for (int i = 0; i < 16; i++) {
        acc[i] += __shfl_xor(acc[i], 8, 64);
        acc[i] += __shfl_xor(acc[i], 16, 64);
        acc[i] += __shfl_xor(acc[i], 32, 64);
    }

    // each lane owns cols col, col+1 where col = 16*lc + 2*sub
    const int col = (lc << 4) + (sub << 1);
    const unsigned short selfw = *(const unsigned short*)&hs8[(long)v * HID + col];
    f32x2 sf = __builtin_amdgcn_cvt_pk_f32_fp8((unsigned int)selfw, false);
    const float sx = acc[(sub << 1) + 0] + sf.x;
    const float sy = acc[(sub << 1) + 1] + sf.y;
    const float dv = dis[v] * 0.125f;   // undo the x8 message scale
    const float rx = fmaxf(fmaf(dv, sx, bias[col]), 0.f);
    const float ry = fmaxf(fmaf(dv, sy, bias[col + 1]), 0.f);
    if (POOL) {
        const int g = batch[v];
        unsafeAtomicAdd(&sums[g * HID + col], rx);
        unsafeAtomicAdd(&sums[g * HID + col + 1], ry);
        if (lane == 0) atomicAdd(&cnt[g], 1);
    } else {
        const unsigned int pk = (unsigned int)f2bf(rx) | ((unsigned int)f2bf(ry) << 16);
        buf[(long)v * (HID / 2) + (col >> 1)] = pk;      // col is even
    }
}

// ---------------- mean + MLP head ----------------
__global__ __launch_bounds__(64) void mlp_kernel(const float* __restrict__ sums,
                                                 const int* __restrict__ cnt,
                                                 const float* __restrict__ Wl1,
                                                 const float* __restrict__ bl1,
                                                 const float* __restrict__ Wl2,
                                                 const float* __restrict__ bl2,
                                                 float* __restrict__ out) {
    const int g = blockIdx.x, t = threadIdx.x;
    __shared__ float mean[HID];
    __shared__ float hid[64];
    const float c = fmaxf((float)cnt[g], 1.0f);
    mean[t] = sums[g * HID + t] / c;
    mean[t + 64] = sums[g * HID + 64 + t] / c;
    __syncthreads();
    float acc = bl1[t];
#pragma unroll 4
    for (int k = 0; k < HID; k++) acc = fmaf(mean[k], Wl1[k * 64 + t], acc);
    hid[t] = fmaxf(acc, 0.f);
    __syncthreads();
    if (t < 5) {
        float a = bl2[t];
#pragma unroll 4
        for (int k = 0; k < 64; k++) a = fmaf(hid[k], Wl2[k * 5 + t], a);
        out[g * 5 + t] = 1.f / (1.f + expf(-a));
    }
}

extern "C" void kernel_launch(void* const* d_in, const int* in_sizes, int n_in,
                              void* d_out, int out_size, void* d_ws, size_t ws_size,
                              hipStream_t stream) {
    const float* x   = (const float*)d_in[0];
    const int* ei    = (const int*)d_in[1];
    const int* batch = (const int*)d_in[2];
    const float* W1  = (const float*)d_in[3];
    const float* b1  = (const float*)d_in[4];
    const float* W2  = (const float*)d_in[5];
    const float* b2  = (const float*)d_in[6];
    const float* Wl1 = (const float*)d_in[7];
    const float* bl1 = (const float*)d_in[8];
    const float* Wl2 = (const float*)d_in[9];
    const float* bl2 = (const float*)d_in[10];
    float* out = (float*)d_out;

    const int n = in_sizes[0] / IN_DIM;       // 50000
    const int E = in_sizes[1] / 2;            // 1600000
    const int* src = ei;
    const int* dst = ei + E;

    char* ws = (char*)d_ws;
    size_t off = 0;
    auto alloc = [&](size_t bytes) {
        void* p = ws + off;
        off = (off + bytes + 255) & ~(size_t)255;
        return p;
    };
    int*   deg       = (int*)alloc((size_t)n * 4);
    float* dis       = (float*)alloc((size_t)n * 4);
    int*   row       = (int*)alloc((size_t)(n + 1) * 4);
    int*   cursor    = (int*)alloc((size_t)n * 4);
    unsigned short* csr16 = (unsigned short*)alloc((size_t)E * 2);
    int*   blockSums = (int*)alloc(256 * 4);
    unsigned char* hs8 = (unsigned char*)alloc((size_t)n * HID);       // fp8 messages
    unsigned int* buf1 = (unsigned int*)alloc((size_t)n * HID * 2);    // bf16 inter-layer h
    unsigned short* w8_1 = (unsigned short*)alloc((size_t)IN_DIM * HID * 2);  // W1 bf16 frags
    unsigned short* w8_2 = (unsigned short*)alloc((size_t)HID * HID * 2);     // W2 bf16 frags
    float* sums = (float*)alloc((size_t)NGRAPH * HID * 4);             // 256-mult ->
    int*   cnt  = (int*)alloc((size_t)NGRAPH * 4);                     // contiguous with sums
    (void)ws_size;

    const int nb = (n + 1023) / 1024;
    const int gemmBlocks = (n + 63) / 64;
    const int aggBlocks  = (n + 3) / 4;
    const int edgeBlocks2 = (E / 2 + 255) / 256;     // int2-vectorized edge kernels

    // --- zero deg + (sums,cnt contiguous: one memset) ---
    hipMemsetAsync(deg, 0, (size_t)n * 4, stream);
    hipMemsetAsync(sums, 0, (size_t)NGRAPH * HID * 4 + (size_t)NGRAPH * 4, stream);

    // --- pack W1/W2 into bf16 MFMA fragment order (one-time) ---
    pack_w<<<32, 256, 0, stream>>>(W1, W2, w8_1, w8_2);

    // --- degree / norm / CSR (multi-block scan chain; dis fused into scan_part) ---
    deg_kernel<<<edgeBlocks2, 256, 0, stream>>>(dst, deg, E);
    scan_part<<<nb, 256, 0, stream>>>(deg, row, blockSums, dis, n);
    scan_tops<<<1, 64, 0, stream>>>(blockSums, nb);
    scan_add<<<nb, 256, 0, stream>>>(row, cursor, blockSums, n, E);
    // 2 dst-range sweeps (was 4): region 1.6 MB, still L2-resident; 2 fewer dst scans
    {
        const int step = (n + 1) / 2;
        for (int k = 0; k < 2; k++) {
            const int lo = k * step;
            const int hi = (k == 1) ? n : (lo + step);
            fill_kernel<<<edgeBlocks2, 256, 0, stream>>>(src, dst, cursor, csr16, E, lo, hi);
        }
    }

    // --- conv1 (bf16 MFMA) ---
    gemm_mfma<IN_DIM, false><<<gemmBlocks, 256, 0, stream>>>(x, w8_1, dis, (unsigned int*)hs8, n);
    agg_kernel<false><<<aggBlocks, 256, 0, stream>>>(hs8, csr16, row, dis, b1, batch,
                                                     buf1, nullptr, nullptr, n);

    // --- conv2 (bf16 MFMA; pool fused in agg) ---
    gemm_mfma<HID, true><<<gemmBlocks, 256, 0, stream>>>(buf1, w8_2, dis, (unsigned int*)hs8, n);
    agg_kernel<true><<<aggBlocks, 256, 0, stream>>>(hs8, csr16, row, dis, b2, batch,
                                                    nullptr, sums, cnt, n);

    // --- head ---
    mlp_kernel<<<NGRAPH, 64, 0, stream>>>(sums, cnt, Wl1, bl1, Wl2, bl2, out);
}